// Round 3
// baseline (1700.989 us; speedup 1.0000x reference)
//
#include <hip/hip_runtime.h>
#include <stdint.h>

#define NB   256      // batch
#define NS   196      // seq len (= hidden seq)
#define NF   384      // in/out features
#define NH   8        // heads
#define NEH  48       // per-head dim
#define NIT  10
#define SP   224      // padded seq (14 tiles of 16)
#define EP   64       // padded per-head dim (K padding; N uses exactly 48)
#define NBH  2048     // NB*NH
#define NBS  50176    // NB*NS

using f32x4  = __attribute__((ext_vector_type(4))) float;
using u16x8  = __attribute__((ext_vector_type(8))) uint16_t;
using u16x4  = __attribute__((ext_vector_type(4))) uint16_t;
using bf16x8 = __attribute__((ext_vector_type(8))) __bf16;

static __device__ __forceinline__ float bf2f(uint16_t u){
  union { uint32_t u32; float f; } c; c.u32 = (uint32_t)u << 16; return c.f;
}
static __device__ __forceinline__ uint16_t f2bf(float f){
  union { float f; uint32_t u32; } c; c.f = f;
  return (uint16_t)((c.u32 + 0x7fffu + ((c.u32 >> 16) & 1u)) >> 16);
}
static __device__ __forceinline__ bf16x8 ld8(const uint16_t* p){
  return __builtin_bit_cast(bf16x8, *(const u16x8*)p);
}
// in-wave LDS write->read ordering (cross-lane through per-wave staging)
static __device__ __forceinline__ void lds_fence(){
  asm volatile("s_waitcnt lgkmcnt(0)" ::: "memory");
}
#define MFMA16(a,b,c) __builtin_amdgcn_mfma_f32_16x16x32_bf16((a),(b),(c),0,0,0)

// ---------------- prep kernels ----------------

__global__ void k_prep_gw(const float* __restrict__ gw, uint16_t* __restrict__ gw_b,
                          uint16_t* __restrict__ gwt_b){
  int idx = blockIdx.x * 256 + threadIdx.x;
  if (idx >= NH*SP*SP) return;
  int h = idx / (SP*SP);
  int r = (idx / SP) % SP;   // o
  int c = idx % SP;          // i
  float v = (r < NS && c < NS) ? gw[((size_t)h*NS + r)*NS + c] : 0.f;
  uint16_t bv = f2bf(v);
  gw_b[idx] = bv;
  gwt_b[((size_t)h*SP + c)*SP + r] = bv;
}

__global__ void k_prep_small(const float* __restrict__ lw, const float* __restrict__ ew,
                             const float* __restrict__ ow,
                             uint16_t* __restrict__ lw_b, uint16_t* __restrict__ lwt_b,
                             uint16_t* __restrict__ ew_b, uint16_t* __restrict__ ow_b){
  int idx = blockIdx.x * 256 + threadIdx.x;
  if (idx < EP*EP){
    int f = idx >> 6, e = idx & 63;
    float v = (f < NEH && e < NEH) ? lw[f*NEH + e] : 0.f;
    uint16_t bv = f2bf(v);
    lw_b[f*EP + e] = bv;     // [f][e]
    lwt_b[e*EP + f] = bv;    // [e][f]
  }
  if (idx < NF*NF){
    ew_b[idx] = f2bf(ew[idx]);
    ow_b[idx] = f2bf(ow[idx]);
  }
}

__global__ void k_prep_h(const float* __restrict__ h0, uint16_t* __restrict__ h_b){
  int idx = blockIdx.x * 256 + threadIdx.x;
  if (idx >= NBH*SP) return;
  int bh = idx / SP, o = idx % SP;
  int b = bh >> 3, h = bh & 7;
  uint16_t* dst = h_b + (size_t)idx * EP;
  if (o < NS){
    const float* src = h0 + (((size_t)(b*NS + o))*NH + h)*NEH;
    float s = 0.f;
    float v[48];
    #pragma unroll
    for (int j = 0; j < NEH; ++j){ v[j] = src[j]; s += fabsf(v[j]); }
    s = fmaxf(s, 1e-12f);
    float inv = 1.f / s;
    #pragma unroll
    for (int j = 0; j < NEH; ++j) dst[j] = f2bf(v[j] * inv);
    #pragma unroll
    for (int j = NEH; j < EP; ++j) dst[j] = 0;
  } else {
    #pragma unroll
    for (int j = 0; j < EP; ++j) dst[j] = 0;
  }
}

// ---------------- embed GEMM + input prep ----------------
__global__ __launch_bounds__(256) void k_embed(const float* __restrict__ x,
    const uint16_t* __restrict__ ew_b, const float* __restrict__ eb,
    uint16_t* __restrict__ inp_ws){
  const int wave = threadIdx.x >> 6, lane = threadIdx.x & 63;
  const int lg = lane >> 4, li = lane & 15;
  const int m0 = blockIdx.x * 64 + wave * 16;
  f32x4 acc[24];
  #pragma unroll
  for (int i = 0; i < 24; ++i) acc[i] = (f32x4)0.0f;
  const float* ap = x + (size_t)(m0 + li) * NF + 8*lg;
  for (int kt = 0; kt < 12; ++kt){
    f32x4 a0 = *(const f32x4*)(ap + kt*32);
    f32x4 a1 = *(const f32x4*)(ap + kt*32 + 4);
    u16x8 au;
    #pragma unroll
    for (int j = 0; j < 4; ++j){ au[j] = f2bf(a0[j]); au[j+4] = f2bf(a1[j]); }
    bf16x8 a = __builtin_bit_cast(bf16x8, au);
    #pragma unroll
    for (int nt = 0; nt < 24; ++nt){
      bf16x8 b = ld8(ew_b + (size_t)(nt*16 + li)*NF + kt*32 + 8*lg);
      acc[nt] = MFMA16(a, b, acc[nt]);
    }
  }
  #pragma unroll
  for (int hh = 0; hh < 8; ++hh){
    float xec[3][4];
    float s[4] = {0.f, 0.f, 0.f, 0.f};
    #pragma unroll
    for (int j = 0; j < 3; ++j){
      int nt = hh*3 + j;
      float bias = eb[nt*16 + li];
      #pragma unroll
      for (int r = 0; r < 4; ++r){
        float v = fmaxf(acc[nt][r] + bias, 1e-6f);
        xec[j][r] = v; s[r] += v;
      }
    }
    #pragma unroll
    for (int r = 0; r < 4; ++r){
      float t = s[r];
      t += __shfl_xor(t, 1); t += __shfl_xor(t, 2);
      t += __shfl_xor(t, 4); t += __shfl_xor(t, 8);
      s[r] = t;
    }
    #pragma unroll
    for (int r = 0; r < 4; ++r){
      int m = m0 + 4*lg + r;
      int b = m / NS, si = m - b*NS;
      float inv = 1.f / s[r];
      #pragma unroll
      for (int j = 0; j < 3; ++j){
        inp_ws[((size_t)(b*NH + hh)*NS + si)*EP + j*16 + li] = f2bf(xec[j][r] * inv);
      }
    }
  }
}

// ---------------- main NNMF fixed-point kernel ----------------
// One block per (b,h). 7 waves, 2 tiles/wave (14 tiles incl. zero pad tile 13).
// Steps 1-2-ratio-4 are wave-local (per-wave LDS staging, in-wave lgkmcnt
// ordering); only 2 block barriers per iteration (t2T ready / hT ready).
__global__ __launch_bounds__(448, 4) void k_main(
    const uint16_t* __restrict__ gw_b,   // [H][SP][SP] (o,i)
    const uint16_t* __restrict__ gwt_b,  // [H][SP][SP] (i,o)
    const uint16_t* __restrict__ lw_b,   // [EP][EP] (f,e)
    const uint16_t* __restrict__ lwt_b,  // [EP][EP] (e,f)
    const uint16_t* __restrict__ inp_ws, // [BH][NS][EP]
    uint16_t* __restrict__ h_b)          // [BH][SP][EP]
{
  __shared__ __align__(16) uint16_t hT [48][232];        // h transposed [f][o]
  __shared__ __align__(16) uint16_t t2T[48][232];        // t2 transposed [f][i]
  __shared__ __align__(16) uint16_t Sg[7][2][16][72];    // per-wave staging, dbuf

  const int bh = blockIdx.x;
  const int hh = bh & 7;
  const int tid = threadIdx.x;
  const int wave = tid >> 6;
  const int lane = tid & 63;
  const int lg = lane >> 4;
  const int li = lane & 15;
  const int tt[2] = {wave, wave + 7};

  // zero hT (pad-col invariant) + staging K-pad cols 48..63 (never rewritten)
  {
    uint32_t* p = (uint32_t*)&hT[0][0];
    for (int i = tid; i < 48*232/2; i += 448) p[i] = 0u;
    u16x4 z = {0,0,0,0};
    *(u16x4*)&Sg[wave][0][li][48 + 4*lg] = z;
    *(u16x4*)&Sg[wave][1][li][48 + 4*lg] = z;
  }

  // preload h (fp32 state) and inp (iteration-invariant), D-fragment layout:
  // row = tile*16 + 4*lg + r, col = nt*16 + li
  uint16_t* __restrict__ hrow = h_b + (size_t)bh * SP * EP;
  const uint16_t* __restrict__ inr = inp_ws + (size_t)bh * NS * EP;
  float hr[2][3][4], inpf[2][3][4];
  uint16_t hraw[2][3][4];
  #pragma unroll
  for (int tp = 0; tp < 2; ++tp){
    int t = tt[tp];
    #pragma unroll
    for (int nt = 0; nt < 3; ++nt)
      #pragma unroll
      for (int r = 0; r < 4; ++r){
        int row = t*16 + 4*lg + r;
        uint16_t u = hrow[(size_t)row*EP + nt*16 + li];
        hraw[tp][nt][r] = u;
        hr[tp][nt][r] = bf2f(u);
        inpf[tp][nt][r] = (row < NS) ? bf2f(inr[(size_t)row*EP + nt*16 + li]) : 0.f;
      }
  }
  __syncthreads();   // hT zeroing complete

  // hT init (transposed store of the bf16 h fragments)
  #pragma unroll
  for (int tp = 0; tp < 2; ++tp){
    int ob = tt[tp]*16 + 4*lg;
    if (ob < NS){
      #pragma unroll
      for (int nt = 0; nt < 3; ++nt){
        u16x4 w;
        #pragma unroll
        for (int r = 0; r < 4; ++r) w[r] = hraw[tp][nt][r];
        *(u16x4*)&hT[nt*16 + li][ob] = w;
      }
    }
  }

  // local-weight B-fragments (constant)
  bf16x8 lwtF[3][2], lwF[3][2];
  #pragma unroll
  for (int nt = 0; nt < 3; ++nt)
    #pragma unroll
    for (int kt = 0; kt < 2; ++kt){
      lwtF[nt][kt] = ld8(lwt_b + (size_t)(nt*16 + li)*EP + kt*32 + 8*lg);
      lwF [nt][kt] = ld8(lw_b  + (size_t)(nt*16 + li)*EP + kt*32 + 8*lg);
    }

  const uint16_t* __restrict__ gwh  = gw_b  + (size_t)hh * SP * SP;
  const uint16_t* __restrict__ gwth = gwt_b + (size_t)hh * SP * SP;
  __syncthreads();   // hT init visible

  for (int it = 0; it < NIT; ++it){
    // ---- A1: step1 for both tiles: t1[i][f] = sum_o gwt[i][o]*h[o][f]
    f32x4 a1[2][3];
    #pragma unroll
    for (int tp = 0; tp < 2; ++tp){
      #pragma unroll
      for (int i = 0; i < 3; ++i) a1[tp][i] = (f32x4)0.0f;
      const uint16_t* gA = gwth + (size_t)(tt[tp]*16 + li)*SP + 8*lg;
      #pragma unroll
      for (int kt = 0; kt < 7; ++kt){
        bf16x8 a = ld8(gA + kt*32);
        #pragma unroll
        for (int nt = 0; nt < 3; ++nt)
          a1[tp][nt] = MFMA16(a, ld8(&hT[nt*16 + li][kt*32 + 8*lg]), a1[tp][nt]);
      }
    }

    // ---- A2 per tile (wave-local): transpose -> step2 -> ratio -> step4 -> t2T
    #pragma unroll
    for (int tp = 0; tp < 2; ++tp){
      int t = tt[tp];
      #pragma unroll
      for (int nt = 0; nt < 3; ++nt)
        #pragma unroll
        for (int r = 0; r < 4; ++r)
          Sg[wave][tp][4*lg + r][nt*16 + li] = f2bf(a1[tp][nt][r]);
      lds_fence();
      // step2: rec = t1 x lwt
      f32x4 rec[3];
      #pragma unroll
      for (int i = 0; i < 3; ++i) rec[i] = (f32x4)0.0f;
      #pragma unroll
      for (int kt = 0; kt < 2; ++kt){
        bf16x8 a = ld8(&Sg[wave][tp][li][kt*32 + 8*lg]);
        #pragma unroll
        for (int nt = 0; nt < 3; ++nt) rec[nt] = MFMA16(a, lwtF[nt][kt], rec[nt]);
      }
      // ratio = inp * rowsum(clip(rec)) / clip(rec)
      float s[4] = {0.f,0.f,0.f,0.f};
      float rv[3][4];
      #pragma unroll
      for (int nt = 0; nt < 3; ++nt)
        #pragma unroll
        for (int r = 0; r < 4; ++r){
          float v = fmaxf(rec[nt][r], 1e-6f);
          rv[nt][r] = v; s[r] += v;
        }
      #pragma unroll
      for (int r = 0; r < 4; ++r){
        float v = s[r];
        v += __shfl_xor(v, 1); v += __shfl_xor(v, 2);
        v += __shfl_xor(v, 4); v += __shfl_xor(v, 8);
        s[r] = v;
      }
      #pragma unroll
      for (int nt = 0; nt < 3; ++nt)
        #pragma unroll
        for (int r = 0; r < 4; ++r)
          Sg[wave][tp][4*lg + r][nt*16 + li] = f2bf(inpf[tp][nt][r] * s[r] / rv[nt][r]);
      lds_fence();
      // step4: t2 = ratio x lw
      f32x4 t2[3];
      #pragma unroll
      for (int i = 0; i < 3; ++i) t2[i] = (f32x4)0.0f;
      #pragma unroll
      for (int kt = 0; kt < 2; ++kt){
        bf16x8 a = ld8(&Sg[wave][tp][li][kt*32 + 8*lg]);
        #pragma unroll
        for (int nt = 0; nt < 3; ++nt) t2[nt] = MFMA16(a, lwF[nt][kt], t2[nt]);
      }
      // transposed store into t2T [f][i]
      #pragma unroll
      for (int nt = 0; nt < 3; ++nt){
        u16x4 w;
        #pragma unroll
        for (int r = 0; r < 4; ++r) w[r] = f2bf(t2[nt][r]);
        *(u16x4*)&t2T[nt*16 + li][t*16 + 4*lg] = w;
      }
    }
    __syncthreads();   // t2T complete

    // ---- B: step5: hu[o][f] = sum_i gw[o][i]*t2[i][f]; h = norm(clip(h*hu))
    #pragma unroll
    for (int tp = 0; tp < 2; ++tp){
      int t = tt[tp];
      f32x4 hu[3];
      #pragma unroll
      for (int i = 0; i < 3; ++i) hu[i] = (f32x4)0.0f;
      const uint16_t* gA = gwh + (size_t)(t*16 + li)*SP + 8*lg;
      #pragma unroll
      for (int kt = 0; kt < 7; ++kt){
        bf16x8 a = ld8(gA + kt*32);
        #pragma unroll
        for (int nt = 0; nt < 3; ++nt)
          hu[nt] = MFMA16(a, ld8(&t2T[nt*16 + li][kt*32 + 8*lg]), hu[nt]);
      }
      float s[4] = {0.f,0.f,0.f,0.f};
      #pragma unroll
      for (int nt = 0; nt < 3; ++nt)
        #pragma unroll
        for (int r = 0; r < 4; ++r){
          float v = fmaxf(hr[tp][nt][r] * hu[nt][r], 1e-6f);
          hr[tp][nt][r] = v; s[r] += v;
        }
      #pragma unroll
      for (int r = 0; r < 4; ++r){
        float v = s[r];
        v += __shfl_xor(v, 1); v += __shfl_xor(v, 2);
        v += __shfl_xor(v, 4); v += __shfl_xor(v, 8);
        s[r] = v;
      }
      int ob = t*16 + 4*lg;
      #pragma unroll
      for (int nt = 0; nt < 3; ++nt){
        u16x4 w;
        #pragma unroll
        for (int r = 0; r < 4; ++r){
          hr[tp][nt][r] *= 1.f / s[r];
          w[r] = f2bf(hr[tp][nt][r]);
        }
        if (ob < NS) *(u16x4*)&hT[nt*16 + li][ob] = w;
      }
    }
    __syncthreads();   // hT complete for next iteration
  }

  // write back h (rows <196; pad rows in h_b already zeroed by prep)
  for (int idx = tid; idx < NS*8; idx += 448){
    int o = idx >> 3, f8 = (idx & 7) << 3;
    u16x8 v;
    #pragma unroll
    for (int j = 0; j < 8; ++j) v[j] = hT[f8+j][o];
    *(u16x8*)(hrow + (size_t)o*EP + f8) = v;
  }
}

// ---------------- output GEMM ----------------
__global__ __launch_bounds__(256) void k_out(const uint16_t* __restrict__ h_b,
    const uint16_t* __restrict__ ow_b, const float* __restrict__ obv,
    float* __restrict__ out){
  const int wave = threadIdx.x >> 6, lane = threadIdx.x & 63;
  const int lg = lane >> 4, li = lane & 15;
  const int m0 = blockIdx.x * 64 + wave * 16;
  const int m = m0 + li;
  const int b = m / NS, si = m - b*NS;
  f32x4 acc[24];
  #pragma unroll
  for (int i = 0; i < 24; ++i) acc[i] = (f32x4)0.0f;
  for (int kt = 0; kt < 12; ++kt){
    int ks = kt*32 + 8*lg;
    int hh = ks / NEH, f = ks - hh*NEH;
    bf16x8 a = ld8(h_b + ((size_t)(b*NH + hh)*SP + si)*EP + f);
    #pragma unroll
    for (int nt = 0; nt < 24; ++nt){
      bf16x8 bb = ld8(ow_b + (size_t)(nt*16 + li)*NF + kt*32 + 8*lg);
      acc[nt] = MFMA16(a, bb, acc[nt]);
    }
  }
  #pragma unroll
  for (int nt = 0; nt < 24; ++nt){
    float bias = obv[nt*16 + li];
    #pragma unroll
    for (int r = 0; r < 4; ++r)
      out[(size_t)(m0 + 4*lg + r)*NF + nt*16 + li] = acc[nt][r] + bias;
  }
}

// ---------------- launch ----------------
extern "C" void kernel_launch(void* const* d_in, const int* in_sizes, int n_in,
                              void* d_out, int out_size, void* d_ws, size_t ws_size,
                              hipStream_t stream){
  const float* x   = (const float*)d_in[0];
  const float* h0  = (const float*)d_in[1];
  const float* ew  = (const float*)d_in[2];
  const float* eb  = (const float*)d_in[3];
  const float* lw  = (const float*)d_in[4];
  const float* gw  = (const float*)d_in[5];
  const float* ow  = (const float*)d_in[6];
  const float* obv = (const float*)d_in[7];
  float* out = (float*)d_out;

  char* w = (char*)d_ws;
  size_t o_inp = 0;
  size_t o_hb  = o_inp + (size_t)NBH*NS*EP*2;
  size_t o_gw  = o_hb  + (size_t)NBH*SP*EP*2;
  size_t o_gwt = o_gw  + (size_t)NH*SP*SP*2;
  size_t o_lw  = o_gwt + (size_t)NH*SP*SP*2;
  size_t o_lwt = o_lw  + (size_t)EP*EP*2;
  size_t o_ew  = o_lwt + (size_t)EP*EP*2;
  size_t o_ow  = o_ew  + (size_t)NF*NF*2;
  size_t total = o_ow  + (size_t)NF*NF*2;
  if (ws_size < total) return;

  uint16_t* inp_ws = (uint16_t*)(w + o_inp);
  uint16_t* h_b    = (uint16_t*)(w + o_hb);
  uint16_t* gw_b   = (uint16_t*)(w + o_gw);
  uint16_t* gwt_b  = (uint16_t*)(w + o_gwt);
  uint16_t* lw_b   = (uint16_t*)(w + o_lw);
  uint16_t* lwt_b  = (uint16_t*)(w + o_lwt);
  uint16_t* ew_b   = (uint16_t*)(w + o_ew);
  uint16_t* ow_b   = (uint16_t*)(w + o_ow);

  k_prep_gw<<<(NH*SP*SP + 255)/256, 256, 0, stream>>>(gw, gw_b, gwt_b);
  k_prep_small<<<(NF*NF + 255)/256, 256, 0, stream>>>(lw, ew, ow, lw_b, lwt_b, ew_b, ow_b);
  k_prep_h<<<(NBH*SP + 255)/256, 256, 0, stream>>>(h0, h_b);
  k_embed<<<NBS/64, 256, 0, stream>>>(x, ew_b, eb, inp_ws);
  k_main<<<NBH, 448, 0, stream>>>(gw_b, gwt_b, lw_b, lwt_b, inp_ws, h_b);
  k_out<<<NBS/64, 256, 0, stream>>>(h_b, ow_b, obv, out);
}

// Round 4
// 1598.924 us; speedup vs baseline: 1.0638x; 1.0638x over previous
//
#include <hip/hip_runtime.h>
#include <stdint.h>

#define NB   256      // batch
#define NS   196      // seq len (= hidden seq)
#define NF   384      // in/out features
#define NH   8        // heads
#define NEH  48       // per-head dim
#define NIT  10
#define SP   224      // padded seq (14 tiles of 16)
#define EP   64       // padded per-head dim (K padding; N uses exactly 48)
#define NBH  2048     // NB*NH
#define NBS  50176    // NB*NS

using f32x4  = __attribute__((ext_vector_type(4))) float;
using u16x8  = __attribute__((ext_vector_type(8))) uint16_t;
using u16x4  = __attribute__((ext_vector_type(4))) uint16_t;
using bf16x8 = __attribute__((ext_vector_type(8))) __bf16;

static __device__ __forceinline__ float bf2f(uint16_t u){
  union { uint32_t u32; float f; } c; c.u32 = (uint32_t)u << 16; return c.f;
}
static __device__ __forceinline__ uint16_t f2bf(float f){
  union { float f; uint32_t u32; } c; c.f = f;
  return (uint16_t)((c.u32 + 0x7fffu + ((c.u32 >> 16) & 1u)) >> 16);
}
static __device__ __forceinline__ bf16x8 ld8(const uint16_t* p){
  return __builtin_bit_cast(bf16x8, *(const u16x8*)p);
}
// in-wave LDS write->read ordering (cross-lane through per-wave staging)
static __device__ __forceinline__ void lds_fence(){
  asm volatile("s_waitcnt lgkmcnt(0)" ::: "memory");
}
#define MFMA16(a,b,c) __builtin_amdgcn_mfma_f32_16x16x32_bf16((a),(b),(c),0,0,0)

// ---------------- prep kernels ----------------

__global__ void k_prep_gw(const float* __restrict__ gw, uint16_t* __restrict__ gw_b,
                          uint16_t* __restrict__ gwt_b){
  int idx = blockIdx.x * 256 + threadIdx.x;
  if (idx >= NH*SP*SP) return;
  int h = idx / (SP*SP);
  int r = (idx / SP) % SP;   // o
  int c = idx % SP;          // i
  float v = (r < NS && c < NS) ? gw[((size_t)h*NS + r)*NS + c] : 0.f;
  uint16_t bv = f2bf(v);
  gw_b[idx] = bv;
  gwt_b[((size_t)h*SP + c)*SP + r] = bv;
}

__global__ void k_prep_small(const float* __restrict__ lw, const float* __restrict__ ew,
                             const float* __restrict__ ow,
                             uint16_t* __restrict__ lw_b, uint16_t* __restrict__ lwt_b,
                             uint16_t* __restrict__ ew_b, uint16_t* __restrict__ ow_b){
  int idx = blockIdx.x * 256 + threadIdx.x;
  if (idx < EP*EP){
    int f = idx >> 6, e = idx & 63;
    float v = (f < NEH && e < NEH) ? lw[f*NEH + e] : 0.f;
    uint16_t bv = f2bf(v);
    lw_b[f*EP + e] = bv;     // [f][e]
    lwt_b[e*EP + f] = bv;    // [e][f]
  }
  if (idx < NF*NF){
    ew_b[idx] = f2bf(ew[idx]);
    ow_b[idx] = f2bf(ow[idx]);
  }
}

__global__ void k_prep_h(const float* __restrict__ h0, uint16_t* __restrict__ h_b){
  int idx = blockIdx.x * 256 + threadIdx.x;
  if (idx >= NBH*SP) return;
  int bh = idx / SP, o = idx % SP;
  int b = bh >> 3, h = bh & 7;
  uint16_t* dst = h_b + (size_t)idx * EP;
  if (o < NS){
    const float* src = h0 + (((size_t)(b*NS + o))*NH + h)*NEH;
    float s = 0.f;
    float v[48];
    #pragma unroll
    for (int j = 0; j < NEH; ++j){ v[j] = src[j]; s += fabsf(v[j]); }
    s = fmaxf(s, 1e-12f);
    float inv = 1.f / s;
    #pragma unroll
    for (int j = 0; j < NEH; ++j) dst[j] = f2bf(v[j] * inv);
    #pragma unroll
    for (int j = NEH; j < EP; ++j) dst[j] = 0;
  } else {
    #pragma unroll
    for (int j = 0; j < EP; ++j) dst[j] = 0;
  }
}

// ---------------- embed GEMM + input prep ----------------
__global__ __launch_bounds__(256) void k_embed(const float* __restrict__ x,
    const uint16_t* __restrict__ ew_b, const float* __restrict__ eb,
    uint16_t* __restrict__ inp_ws){
  const int wave = threadIdx.x >> 6, lane = threadIdx.x & 63;
  const int lg = lane >> 4, li = lane & 15;
  const int m0 = blockIdx.x * 64 + wave * 16;
  f32x4 acc[24];
  #pragma unroll
  for (int i = 0; i < 24; ++i) acc[i] = (f32x4)0.0f;
  const float* ap = x + (size_t)(m0 + li) * NF + 8*lg;
  for (int kt = 0; kt < 12; ++kt){
    f32x4 a0 = *(const f32x4*)(ap + kt*32);
    f32x4 a1 = *(const f32x4*)(ap + kt*32 + 4);
    u16x8 au;
    #pragma unroll
    for (int j = 0; j < 4; ++j){ au[j] = f2bf(a0[j]); au[j+4] = f2bf(a1[j]); }
    bf16x8 a = __builtin_bit_cast(bf16x8, au);
    #pragma unroll
    for (int nt = 0; nt < 24; ++nt){
      bf16x8 b = ld8(ew_b + (size_t)(nt*16 + li)*NF + kt*32 + 8*lg);
      acc[nt] = MFMA16(a, b, acc[nt]);
    }
  }
  #pragma unroll
  for (int hh = 0; hh < 8; ++hh){
    float xec[3][4];
    float s[4] = {0.f, 0.f, 0.f, 0.f};
    #pragma unroll
    for (int j = 0; j < 3; ++j){
      int nt = hh*3 + j;
      float bias = eb[nt*16 + li];
      #pragma unroll
      for (int r = 0; r < 4; ++r){
        float v = fmaxf(acc[nt][r] + bias, 1e-6f);
        xec[j][r] = v; s[r] += v;
      }
    }
    #pragma unroll
    for (int r = 0; r < 4; ++r){
      float t = s[r];
      t += __shfl_xor(t, 1); t += __shfl_xor(t, 2);
      t += __shfl_xor(t, 4); t += __shfl_xor(t, 8);
      s[r] = t;
    }
    #pragma unroll
    for (int r = 0; r < 4; ++r){
      int m = m0 + 4*lg + r;
      int b = m / NS, si = m - b*NS;
      float inv = 1.f / s[r];
      #pragma unroll
      for (int j = 0; j < 3; ++j){
        inp_ws[((size_t)(b*NH + hh)*NS + si)*EP + j*16 + li] = f2bf(xec[j][r] * inv);
      }
    }
  }
}

// ---------------- main NNMF fixed-point kernel ----------------
// One block per (b,h). 7 waves, 2 tiles/wave (14 tiles incl. zero pad tile 13).
// Tiles processed SEQUENTIALLY per wave (register-pressure fix vs r3: a1 is
// transient per tile, not held for both). waves_per_eu(4,4): cap VGPR at 128
// AND stop the allocator spilling to chase occupancy LDS already forbids.
__global__ __launch_bounds__(448)
__attribute__((amdgpu_waves_per_eu(4, 4))) void k_main(
    const uint16_t* __restrict__ gw_b,   // [H][SP][SP] (o,i)
    const uint16_t* __restrict__ gwt_b,  // [H][SP][SP] (i,o)
    const uint16_t* __restrict__ lw_b,   // [EP][EP] (f,e)
    const uint16_t* __restrict__ lwt_b,  // [EP][EP] (e,f)
    const uint16_t* __restrict__ inp_ws, // [BH][NS][EP]
    uint16_t* __restrict__ h_b)          // [BH][SP][EP]
{
  __shared__ __align__(16) uint16_t hT [48][232];        // h transposed [f][o]
  __shared__ __align__(16) uint16_t t2T[48][232];        // t2 transposed [f][i]
  __shared__ __align__(16) uint16_t Sg[7][2][16][72];    // per-wave staging

  const int bh = blockIdx.x;
  const int hh = bh & 7;
  const int tid = threadIdx.x;
  const int wave = tid >> 6;
  const int lane = tid & 63;
  const int lg = lane >> 4;
  const int li = lane & 15;
  const int tt[2] = {wave, wave + 7};

  // zero hT (pad-col invariant) + staging K-pad cols 48..63 (never rewritten)
  {
    uint32_t* p = (uint32_t*)&hT[0][0];
    for (int i = tid; i < 48*232/2; i += 448) p[i] = 0u;
    u16x4 z = {0,0,0,0};
    *(u16x4*)&Sg[wave][0][li][48 + 4*lg] = z;
    *(u16x4*)&Sg[wave][1][li][48 + 4*lg] = z;
  }

  // preload h (fp32 state) and inp (iteration-invariant), D-fragment layout:
  // row = tile*16 + 4*lg + r, col = nt*16 + li
  uint16_t* __restrict__ hrow = h_b + (size_t)bh * SP * EP;
  const uint16_t* __restrict__ inr = inp_ws + (size_t)bh * NS * EP;
  float hr[2][3][4], inpf[2][3][4];
  uint16_t hraw[2][3][4];
  #pragma unroll
  for (int tp = 0; tp < 2; ++tp){
    int t = tt[tp];
    #pragma unroll
    for (int nt = 0; nt < 3; ++nt)
      #pragma unroll
      for (int r = 0; r < 4; ++r){
        int row = t*16 + 4*lg + r;
        uint16_t u = hrow[(size_t)row*EP + nt*16 + li];
        hraw[tp][nt][r] = u;
        hr[tp][nt][r] = bf2f(u);
        inpf[tp][nt][r] = (row < NS) ? bf2f(inr[(size_t)row*EP + nt*16 + li]) : 0.f;
      }
  }
  __syncthreads();   // hT zeroing complete

  // hT init (transposed store of the bf16 h fragments)
  #pragma unroll
  for (int tp = 0; tp < 2; ++tp){
    int ob = tt[tp]*16 + 4*lg;
    if (ob < NS){
      #pragma unroll
      for (int nt = 0; nt < 3; ++nt){
        u16x4 w;
        #pragma unroll
        for (int r = 0; r < 4; ++r) w[r] = hraw[tp][nt][r];
        *(u16x4*)&hT[nt*16 + li][ob] = w;
      }
    }
  }

  // local-weight B-fragments (constant)
  bf16x8 lwtF[3][2], lwF[3][2];
  #pragma unroll
  for (int nt = 0; nt < 3; ++nt)
    #pragma unroll
    for (int kt = 0; kt < 2; ++kt){
      lwtF[nt][kt] = ld8(lwt_b + (size_t)(nt*16 + li)*EP + kt*32 + 8*lg);
      lwF [nt][kt] = ld8(lw_b  + (size_t)(nt*16 + li)*EP + kt*32 + 8*lg);
    }

  const uint16_t* __restrict__ gwh  = gw_b  + (size_t)hh * SP * SP;
  const uint16_t* __restrict__ gwth = gwt_b + (size_t)hh * SP * SP;
  __syncthreads();   // hT init visible

  for (int it = 0; it < NIT; ++it){
    // ---- A: per tile (sequential, wave-local):
    //      step1 -> stage -> step2 -> ratio -> step4 -> t2T
    #pragma unroll
    for (int tp = 0; tp < 2; ++tp){
      const int t = tt[tp];
      // step1: t1[i][f] = sum_o gwt[i][o]*h[o][f]
      f32x4 a1[3];
      #pragma unroll
      for (int i = 0; i < 3; ++i) a1[i] = (f32x4)0.0f;
      const uint16_t* gA = gwth + (size_t)(t*16 + li)*SP + 8*lg;
      #pragma unroll
      for (int kt = 0; kt < 7; ++kt){
        bf16x8 a = ld8(gA + kt*32);
        #pragma unroll
        for (int nt = 0; nt < 3; ++nt)
          a1[nt] = MFMA16(a, ld8(&hT[nt*16 + li][kt*32 + 8*lg]), a1[nt]);
      }
      // transpose-stage t1 through per-wave LDS
      #pragma unroll
      for (int nt = 0; nt < 3; ++nt)
        #pragma unroll
        for (int r = 0; r < 4; ++r)
          Sg[wave][tp][4*lg + r][nt*16 + li] = f2bf(a1[nt][r]);
      lds_fence();
      // step2: rec = t1 x lwt
      f32x4 rec[3];
      #pragma unroll
      for (int i = 0; i < 3; ++i) rec[i] = (f32x4)0.0f;
      #pragma unroll
      for (int kt = 0; kt < 2; ++kt){
        bf16x8 a = ld8(&Sg[wave][tp][li][kt*32 + 8*lg]);
        #pragma unroll
        for (int nt = 0; nt < 3; ++nt) rec[nt] = MFMA16(a, lwtF[nt][kt], rec[nt]);
      }
      // ratio = inp * rowsum(clip(rec)) / clip(rec)
      float s[4] = {0.f,0.f,0.f,0.f};
      float rv[3][4];
      #pragma unroll
      for (int nt = 0; nt < 3; ++nt)
        #pragma unroll
        for (int r = 0; r < 4; ++r){
          float v = fmaxf(rec[nt][r], 1e-6f);
          rv[nt][r] = v; s[r] += v;
        }
      #pragma unroll
      for (int r = 0; r < 4; ++r){
        float v = s[r];
        v += __shfl_xor(v, 1); v += __shfl_xor(v, 2);
        v += __shfl_xor(v, 4); v += __shfl_xor(v, 8);
        s[r] = v;
      }
      #pragma unroll
      for (int nt = 0; nt < 3; ++nt)
        #pragma unroll
        for (int r = 0; r < 4; ++r)
          Sg[wave][tp][4*lg + r][nt*16 + li] = f2bf(inpf[tp][nt][r] * s[r] / rv[nt][r]);
      lds_fence();
      // step4: t2 = ratio x lw
      f32x4 t2[3];
      #pragma unroll
      for (int i = 0; i < 3; ++i) t2[i] = (f32x4)0.0f;
      #pragma unroll
      for (int kt = 0; kt < 2; ++kt){
        bf16x8 a = ld8(&Sg[wave][tp][li][kt*32 + 8*lg]);
        #pragma unroll
        for (int nt = 0; nt < 3; ++nt) t2[nt] = MFMA16(a, lwF[nt][kt], t2[nt]);
      }
      // transposed store into t2T [f][i]
      #pragma unroll
      for (int nt = 0; nt < 3; ++nt){
        u16x4 w;
        #pragma unroll
        for (int r = 0; r < 4; ++r) w[r] = f2bf(t2[nt][r]);
        *(u16x4*)&t2T[nt*16 + li][t*16 + 4*lg] = w;
      }
    }
    __syncthreads();   // t2T complete

    // ---- B: step5: hu[o][f] = sum_i gw[o][i]*t2[i][f]; h = norm(clip(h*hu))
    #pragma unroll
    for (int tp = 0; tp < 2; ++tp){
      const int t = tt[tp];
      f32x4 hu[3];
      #pragma unroll
      for (int i = 0; i < 3; ++i) hu[i] = (f32x4)0.0f;
      const uint16_t* gA = gwh + (size_t)(t*16 + li)*SP + 8*lg;
      #pragma unroll
      for (int kt = 0; kt < 7; ++kt){
        bf16x8 a = ld8(gA + kt*32);
        #pragma unroll
        for (int nt = 0; nt < 3; ++nt)
          hu[nt] = MFMA16(a, ld8(&t2T[nt*16 + li][kt*32 + 8*lg]), hu[nt]);
      }
      float s[4] = {0.f,0.f,0.f,0.f};
      #pragma unroll
      for (int nt = 0; nt < 3; ++nt)
        #pragma unroll
        for (int r = 0; r < 4; ++r){
          float v = fmaxf(hr[tp][nt][r] * hu[nt][r], 1e-6f);
          hr[tp][nt][r] = v; s[r] += v;
        }
      #pragma unroll
      for (int r = 0; r < 4; ++r){
        float v = s[r];
        v += __shfl_xor(v, 1); v += __shfl_xor(v, 2);
        v += __shfl_xor(v, 4); v += __shfl_xor(v, 8);
        s[r] = v;
      }
      int ob = t*16 + 4*lg;
      #pragma unroll
      for (int nt = 0; nt < 3; ++nt){
        u16x4 w;
        #pragma unroll
        for (int r = 0; r < 4; ++r){
          hr[tp][nt][r] *= 1.f / s[r];
          w[r] = f2bf(hr[tp][nt][r]);
        }
        if (ob < NS) *(u16x4*)&hT[nt*16 + li][ob] = w;
      }
    }
    __syncthreads();   // hT complete for next iteration
  }

  // write back h (rows <196; pad rows in h_b already zeroed by prep)
  for (int idx = tid; idx < NS*8; idx += 448){
    int o = idx >> 3, f8 = (idx & 7) << 3;
    u16x8 v;
    #pragma unroll
    for (int j = 0; j < 8; ++j) v[j] = hT[f8+j][o];
    *(u16x8*)(hrow + (size_t)o*EP + f8) = v;
  }
}

// ---------------- output GEMM ----------------
__global__ __launch_bounds__(256) void k_out(const uint16_t* __restrict__ h_b,
    const uint16_t* __restrict__ ow_b, const float* __restrict__ obv,
    float* __restrict__ out){
  const int wave = threadIdx.x >> 6, lane = threadIdx.x & 63;
  const int lg = lane >> 4, li = lane & 15;
  const int m0 = blockIdx.x * 64 + wave * 16;
  const int m = m0 + li;
  const int b = m / NS, si = m - b*NS;
  f32x4 acc[24];
  #pragma unroll
  for (int i = 0; i < 24; ++i) acc[i] = (f32x4)0.0f;
  for (int kt = 0; kt < 12; ++kt){
    int ks = kt*32 + 8*lg;
    int hh = ks / NEH, f = ks - hh*NEH;
    bf16x8 a = ld8(h_b + ((size_t)(b*NH + hh)*SP + si)*EP + f);
    #pragma unroll
    for (int nt = 0; nt < 24; ++nt){
      bf16x8 bb = ld8(ow_b + (size_t)(nt*16 + li)*NF + kt*32 + 8*lg);
      acc[nt] = MFMA16(a, bb, acc[nt]);
    }
  }
  #pragma unroll
  for (int nt = 0; nt < 24; ++nt){
    float bias = obv[nt*16 + li];
    #pragma unroll
    for (int r = 0; r < 4; ++r)
      out[(size_t)(m0 + 4*lg + r)*NF + nt*16 + li] = acc[nt][r] + bias;
  }
}

// ---------------- launch ----------------
extern "C" void kernel_launch(void* const* d_in, const int* in_sizes, int n_in,
                              void* d_out, int out_size, void* d_ws, size_t ws_size,
                              hipStream_t stream){
  const float* x   = (const float*)d_in[0];
  const float* h0  = (const float*)d_in[1];
  const float* ew  = (const float*)d_in[2];
  const float* eb  = (const float*)d_in[3];
  const float* lw  = (const float*)d_in[4];
  const float* gw  = (const float*)d_in[5];
  const float* ow  = (const float*)d_in[6];
  const float* obv = (const float*)d_in[7];
  float* out = (float*)d_out;

  char* w = (char*)d_ws;
  size_t o_inp = 0;
  size_t o_hb  = o_inp + (size_t)NBH*NS*EP*2;
  size_t o_gw  = o_hb  + (size_t)NBH*SP*EP*2;
  size_t o_gwt = o_gw  + (size_t)NH*SP*SP*2;
  size_t o_lw  = o_gwt + (size_t)NH*SP*SP*2;
  size_t o_lwt = o_lw  + (size_t)EP*EP*2;
  size_t o_ew  = o_lwt + (size_t)EP*EP*2;
  size_t o_ow  = o_ew  + (size_t)NF*NF*2;
  size_t total = o_ow  + (size_t)NF*NF*2;
  if (ws_size < total) return;

  uint16_t* inp_ws = (uint16_t*)(w + o_inp);
  uint16_t* h_b    = (uint16_t*)(w + o_hb);
  uint16_t* gw_b   = (uint16_t*)(w + o_gw);
  uint16_t* gwt_b  = (uint16_t*)(w + o_gwt);
  uint16_t* lw_b   = (uint16_t*)(w + o_lw);
  uint16_t* lwt_b  = (uint16_t*)(w + o_lwt);
  uint16_t* ew_b   = (uint16_t*)(w + o_ew);
  uint16_t* ow_b   = (uint16_t*)(w + o_ow);

  k_prep_gw<<<(NH*SP*SP + 255)/256, 256, 0, stream>>>(gw, gw_b, gwt_b);
  k_prep_small<<<(NF*NF + 255)/256, 256, 0, stream>>>(lw, ew, ow, lw_b, lwt_b, ew_b, ow_b);
  k_prep_h<<<(NBH*SP + 255)/256, 256, 0, stream>>>(h0, h_b);
  k_embed<<<NBS/64, 256, 0, stream>>>(x, ew_b, eb, inp_ws);
  k_main<<<NBH, 448, 0, stream>>>(gw_b, gwt_b, lw_b, lwt_b, inp_ws, h_b);
  k_out<<<NBS/64, 256, 0, stream>>>(h_b, ow_b, obv, out);
}

// Round 5
// 1105.712 us; speedup vs baseline: 1.5384x; 1.4461x over previous
//
#include <hip/hip_runtime.h>
#include <stdint.h>

#define NB   256      // batch
#define NS   196      // seq len (= hidden seq)
#define NF   384      // in/out features
#define NH   8        // heads
#define NEH  48       // per-head dim
#define NIT  10
#define SP   224      // padded seq (14 tiles of 16)
#define EP   64       // padded per-head dim (K padding; N uses exactly 48)
#define NBH  2048     // NB*NH
#define NBS  50176    // NB*NS
#define NT   13       // inp tiles (rows<196 only)

using f32x4  = __attribute__((ext_vector_type(4))) float;
using u16x8  = __attribute__((ext_vector_type(8))) uint16_t;
using u16x4  = __attribute__((ext_vector_type(4))) uint16_t;
using bf16x8 = __attribute__((ext_vector_type(8))) __bf16;

static __device__ __forceinline__ float bf2f(uint16_t u){
  union { uint32_t u32; float f; } c; c.u32 = (uint32_t)u << 16; return c.f;
}
static __device__ __forceinline__ uint16_t f2bf(float f){
  union { float f; uint32_t u32; } c; c.f = f;
  return (uint16_t)((c.u32 + 0x7fffu + ((c.u32 >> 16) & 1u)) >> 16);
}
static __device__ __forceinline__ bf16x8 ld8(const uint16_t* p){
  return __builtin_bit_cast(bf16x8, *(const u16x8*)p);
}
// in-wave LDS write->read ordering (through per-wave private staging)
static __device__ __forceinline__ void lds_fence(){
  asm volatile("s_waitcnt lgkmcnt(0)" ::: "memory");
}
#define MFMA16(a,b,c) __builtin_amdgcn_mfma_f32_16x16x32_bf16((a),(b),(c),0,0,0)

// ---------------- prep kernels ----------------

__global__ void k_prep_gw(const float* __restrict__ gw, uint16_t* __restrict__ gw_b,
                          uint16_t* __restrict__ gwt_b){
  int idx = blockIdx.x * 256 + threadIdx.x;
  if (idx >= NH*SP*SP) return;
  int h = idx / (SP*SP);
  int r = (idx / SP) % SP;   // o
  int c = idx % SP;          // i
  float v = (r < NS && c < NS) ? gw[((size_t)h*NS + r)*NS + c] : 0.f;
  uint16_t bv = f2bf(v);
  gw_b[idx] = bv;
  gwt_b[((size_t)h*SP + c)*SP + r] = bv;
}

__global__ void k_prep_small(const float* __restrict__ lw, const float* __restrict__ ew,
                             const float* __restrict__ ow,
                             uint16_t* __restrict__ lw_b, uint16_t* __restrict__ lwt_b,
                             uint16_t* __restrict__ ew_b, uint16_t* __restrict__ ow_b){
  int idx = blockIdx.x * 256 + threadIdx.x;
  if (idx < EP*EP){
    int f = idx >> 6, e = idx & 63;
    float v = (f < NEH && e < NEH) ? lw[f*NEH + e] : 0.f;
    uint16_t bv = f2bf(v);
    lw_b[f*EP + e] = bv;     // [f][e]
    lwt_b[e*EP + f] = bv;    // [e][f]
  }
  if (idx < NF*NF){
    ew_b[idx] = f2bf(ew[idx]);
    ow_b[idx] = f2bf(ow[idx]);
  }
}

__global__ void k_prep_h(const float* __restrict__ h0, uint16_t* __restrict__ h_b){
  int idx = blockIdx.x * 256 + threadIdx.x;
  if (idx >= NBH*SP) return;
  int bh = idx / SP, o = idx % SP;
  int b = bh >> 3, h = bh & 7;
  uint16_t* dst = h_b + (size_t)idx * EP;
  if (o < NS){
    const float* src = h0 + (((size_t)(b*NS + o))*NH + h)*NEH;
    float s = 0.f;
    float v[48];
    #pragma unroll
    for (int j = 0; j < NEH; ++j){ v[j] = src[j]; s += fabsf(v[j]); }
    s = fmaxf(s, 1e-12f);
    float inv = 1.f / s;
    #pragma unroll
    for (int j = 0; j < NEH; ++j) dst[j] = f2bf(v[j] * inv);
    #pragma unroll
    for (int j = NEH; j < EP; ++j) dst[j] = 0;
  } else {
    #pragma unroll
    for (int j = 0; j < EP; ++j) dst[j] = 0;
  }
}

// ---------------- embed GEMM + input prep ----------------
// xe = clamp(x @ ew^T + b, 1e-6); inp = xe/rowsum48, written FRAGMENT-MAJOR:
// inp_fm[bh][t][lane][slot], lane=(wi>>2)*16+li, slot=j*4+(wi&3), wi=si%16
__global__ __launch_bounds__(256) void k_embed(const float* __restrict__ x,
    const uint16_t* __restrict__ ew_b, const float* __restrict__ eb,
    uint16_t* __restrict__ inp_fm){
  const int wave = threadIdx.x >> 6, lane = threadIdx.x & 63;
  const int lg = lane >> 4, li = lane & 15;
  const int m0 = blockIdx.x * 64 + wave * 16;
  f32x4 acc[24];
  #pragma unroll
  for (int i = 0; i < 24; ++i) acc[i] = (f32x4)0.0f;
  const float* ap = x + (size_t)(m0 + li) * NF + 8*lg;
  for (int kt = 0; kt < 12; ++kt){
    f32x4 a0 = *(const f32x4*)(ap + kt*32);
    f32x4 a1 = *(const f32x4*)(ap + kt*32 + 4);
    u16x8 au;
    #pragma unroll
    for (int j = 0; j < 4; ++j){ au[j] = f2bf(a0[j]); au[j+4] = f2bf(a1[j]); }
    bf16x8 a = __builtin_bit_cast(bf16x8, au);
    #pragma unroll
    for (int nt = 0; nt < 24; ++nt){
      bf16x8 b = ld8(ew_b + (size_t)(nt*16 + li)*NF + kt*32 + 8*lg);
      acc[nt] = MFMA16(a, b, acc[nt]);
    }
  }
  #pragma unroll
  for (int hh = 0; hh < 8; ++hh){
    float xec[3][4];
    float s[4] = {0.f, 0.f, 0.f, 0.f};
    #pragma unroll
    for (int j = 0; j < 3; ++j){
      int nt = hh*3 + j;
      float bias = eb[nt*16 + li];
      #pragma unroll
      for (int r = 0; r < 4; ++r){
        float v = fmaxf(acc[nt][r] + bias, 1e-6f);
        xec[j][r] = v; s[r] += v;
      }
    }
    #pragma unroll
    for (int r = 0; r < 4; ++r){
      float t = s[r];
      t += __shfl_xor(t, 1); t += __shfl_xor(t, 2);
      t += __shfl_xor(t, 4); t += __shfl_xor(t, 8);
      s[r] = t;
    }
    #pragma unroll
    for (int r = 0; r < 4; ++r){
      int m = m0 + 4*lg + r;
      int b = m / NS, si = m - b*NS;
      int t = si >> 4, wi = si & 15;
      int lanep = (wi >> 2)*16 + li;
      float inv = 1.f / s[r];
      size_t base = ((size_t)((b*NH + hh)*NT + t)*64 + lanep)*12 + (wi & 3);
      #pragma unroll
      for (int j = 0; j < 3; ++j)
        inp_fm[base + j*4] = f2bf(xec[j][r] * inv);
    }
  }
}

// ---------------- main NNMF fixed-point kernel ----------------
// One block per (b,h). 8 waves; tiles {w, w+8} (waves 6,7: 1 tile).
// Associativity: rec = gwT x (h x lw) -- maintain hl = h x lw (hlT in LDS)
// instead of t1. 2 barriers/iter. h fp32 in regs. Persistent regs = 72
// (hr 24 + lwF 24 + lwtF 24), mirroring the r2 config that allocated 128.
__global__ __launch_bounds__(512) void k_main(
    const uint16_t* __restrict__ gw_b,   // [H][SP][SP] (o,i)
    const uint16_t* __restrict__ gwt_b,  // [H][SP][SP] (i,o)
    const uint16_t* __restrict__ lw_b,   // [EP][EP] (f,e)
    const uint16_t* __restrict__ lwt_b,  // [EP][EP] (e,f)
    const uint16_t* __restrict__ inp_fm, // [BH][13][64][12]
    uint16_t* __restrict__ h_b)          // [BH][SP][EP]
{
  __shared__ __align__(16) uint16_t hlT[48][232];      // (h x lw)^T  [e][o]
  __shared__ __align__(16) uint16_t t2T[48][232];      // t2^T        [f][i]
  __shared__ __align__(16) uint16_t Sg[8][2][16][68];  // per-wave staging

  const int bh = blockIdx.x;
  const int hh = bh & 7;
  const int tid = threadIdx.x;
  const int wave = tid >> 6;
  const int lane = tid & 63;
  const int lg = lane >> 4;
  const int li = lane & 15;
  const int ntile = (wave < 6) ? 2 : 1;
  const int tt[2] = {wave, wave + 8};

  // zero staging K-pad cols 48..63 (never rewritten; kt=1 A-frag reads them)
  {
    u16x4 z = {0,0,0,0};
    *(u16x4*)&Sg[wave][0][li][48 + 4*lg] = z;
    *(u16x4*)&Sg[wave][1][li][48 + 4*lg] = z;
  }

  // local-weight B-fragments (constant across iterations)
  bf16x8 lwtF[3][2], lwF[3][2];
  #pragma unroll
  for (int nt = 0; nt < 3; ++nt)
    #pragma unroll
    for (int kt = 0; kt < 2; ++kt){
      lwtF[nt][kt] = ld8(lwt_b + (size_t)(nt*16 + li)*EP + kt*32 + 8*lg); // B[k=f][n=e]
      lwF [nt][kt] = ld8(lw_b  + (size_t)(nt*16 + li)*EP + kt*32 + 8*lg); // B[k=e][n=f]
    }

  // load h into fp32 regs (D-layout: row=t*16+4lg+r, col=nt*16+li) and stage
  uint16_t* __restrict__ hrow = h_b + (size_t)bh * SP * EP;
  float hr[2][3][4];
  #pragma unroll
  for (int tp = 0; tp < 2; ++tp){
    if (tp < ntile){
      const int t = tt[tp];
      #pragma unroll
      for (int nt = 0; nt < 3; ++nt)
        #pragma unroll
        for (int r = 0; r < 4; ++r){
          uint16_t u = hrow[(size_t)(t*16 + 4*lg + r)*EP + nt*16 + li];
          hr[tp][nt][r] = bf2f(u);
          Sg[wave][tp][4*lg + r][nt*16 + li] = u;
        }
    }
  }
  lds_fence();
  // initial hl = h x lw -> hlT
  #pragma unroll
  for (int tp = 0; tp < 2; ++tp){
    if (tp < ntile){
      const int t = tt[tp];
      f32x4 hl[3];
      #pragma unroll
      for (int i = 0; i < 3; ++i) hl[i] = (f32x4)0.0f;
      #pragma unroll
      for (int kt = 0; kt < 2; ++kt){
        bf16x8 a = ld8(&Sg[wave][tp][li][kt*32 + 8*lg]);
        #pragma unroll
        for (int nt = 0; nt < 3; ++nt) hl[nt] = MFMA16(a, lwtF[nt][kt], hl[nt]);
      }
      #pragma unroll
      for (int nt = 0; nt < 3; ++nt){
        u16x4 w;
        #pragma unroll
        for (int r = 0; r < 4; ++r) w[r] = f2bf(hl[nt][r]);
        *(u16x4*)&hlT[nt*16 + li][t*16 + 4*lg] = w;
      }
    }
  }

  const uint16_t* __restrict__ gwh  = gw_b  + (size_t)hh * SP * SP;
  const uint16_t* __restrict__ gwth = gwt_b + (size_t)hh * SP * SP;
  __syncthreads();   // hlT ready

  for (int it = 0; it < NIT; ++it){
    // ---- phase B: rec = gwt x hlT; ratio; t2 = ratio x lw -> t2T
    #pragma unroll
    for (int tp = 0; tp < 2; ++tp){
      if (tp < ntile){
        const int t = tt[tp];
        // prefetch inp fragment (hidden under rec GEMM); tile 13 has no inp
        const uint16_t* ipp = inp_fm +
            ((size_t)(bh*NT + (t < NT ? t : NT-1))*64 + lg*16 + li)*12;
        u16x4 ip0 = *(const u16x4*)(ipp);
        u16x4 ip1 = *(const u16x4*)(ipp + 4);
        u16x4 ip2 = *(const u16x4*)(ipp + 8);
        // rec[i][e] = sum_o gwt[i][o] * hl[o][e]
        f32x4 rec[3];
        #pragma unroll
        for (int i = 0; i < 3; ++i) rec[i] = (f32x4)0.0f;
        const uint16_t* gA = gwth + (size_t)(t*16 + li)*SP + 8*lg;
        #pragma unroll
        for (int kt = 0; kt < 7; ++kt){
          bf16x8 a = ld8(gA + kt*32);
          #pragma unroll
          for (int nt = 0; nt < 3; ++nt)
            rec[nt] = MFMA16(a, ld8(&hlT[nt*16 + li][kt*32 + 8*lg]), rec[nt]);
        }
        // ratio = inp * rowsum(clip(rec)) / clip(rec), staged to Sg
        float s[4] = {0.f,0.f,0.f,0.f};
        float rv[3][4];
        #pragma unroll
        for (int nt = 0; nt < 3; ++nt)
          #pragma unroll
          for (int r = 0; r < 4; ++r){
            float v = fmaxf(rec[nt][r], 1e-6f);
            rv[nt][r] = v; s[r] += v;
          }
        #pragma unroll
        for (int r = 0; r < 4; ++r){
          float v = s[r];
          v += __shfl_xor(v, 1); v += __shfl_xor(v, 2);
          v += __shfl_xor(v, 4); v += __shfl_xor(v, 8);
          s[r] = v;
        }
        #pragma unroll
        for (int r = 0; r < 4; ++r){
          Sg[wave][tp][4*lg + r][ 0 + li] = f2bf(bf2f(ip0[r]) * s[r] / rv[0][r]);
          Sg[wave][tp][4*lg + r][16 + li] = f2bf(bf2f(ip1[r]) * s[r] / rv[1][r]);
          Sg[wave][tp][4*lg + r][32 + li] = f2bf(bf2f(ip2[r]) * s[r] / rv[2][r]);
        }
        lds_fence();
        // t2[i][f] = sum_e ratio[i][e] * lw[f][e] -> t2T
        f32x4 t2[3];
        #pragma unroll
        for (int i = 0; i < 3; ++i) t2[i] = (f32x4)0.0f;
        #pragma unroll
        for (int kt = 0; kt < 2; ++kt){
          bf16x8 a = ld8(&Sg[wave][tp][li][kt*32 + 8*lg]);
          #pragma unroll
          for (int nt = 0; nt < 3; ++nt) t2[nt] = MFMA16(a, lwF[nt][kt], t2[nt]);
        }
        #pragma unroll
        for (int nt = 0; nt < 3; ++nt){
          u16x4 w;
          #pragma unroll
          for (int r = 0; r < 4; ++r) w[r] = f2bf(t2[nt][r]);
          *(u16x4*)&t2T[nt*16 + li][t*16 + 4*lg] = w;
        }
      }
    }
    __syncthreads();   // t2T complete

    // ---- phase C: hu = gw x t2T; h = norm(clip(h*hu)); hl = h x lw -> hlT
    #pragma unroll
    for (int tp = 0; tp < 2; ++tp){
      if (tp < ntile){
        const int t = tt[tp];
        f32x4 hu[3];
        #pragma unroll
        for (int i = 0; i < 3; ++i) hu[i] = (f32x4)0.0f;
        const uint16_t* gA = gwh + (size_t)(t*16 + li)*SP + 8*lg;
        #pragma unroll
        for (int kt = 0; kt < 7; ++kt){
          bf16x8 a = ld8(gA + kt*32);
          #pragma unroll
          for (int nt = 0; nt < 3; ++nt)
            hu[nt] = MFMA16(a, ld8(&t2T[nt*16 + li][kt*32 + 8*lg]), hu[nt]);
        }
        float s[4] = {0.f,0.f,0.f,0.f};
        #pragma unroll
        for (int nt = 0; nt < 3; ++nt)
          #pragma unroll
          for (int r = 0; r < 4; ++r){
            float v = fmaxf(hr[tp][nt][r] * hu[nt][r], 1e-6f);
            hr[tp][nt][r] = v; s[r] += v;
          }
        #pragma unroll
        for (int r = 0; r < 4; ++r){
          float v = s[r];
          v += __shfl_xor(v, 1); v += __shfl_xor(v, 2);
          v += __shfl_xor(v, 4); v += __shfl_xor(v, 8);
          s[r] = 1.f / v;
        }
        #pragma unroll
        for (int nt = 0; nt < 3; ++nt)
          #pragma unroll
          for (int r = 0; r < 4; ++r){
            hr[tp][nt][r] *= s[r];
            Sg[wave][tp][4*lg + r][nt*16 + li] = f2bf(hr[tp][nt][r]);
          }
        lds_fence();
        f32x4 hl[3];
        #pragma unroll
        for (int i = 0; i < 3; ++i) hl[i] = (f32x4)0.0f;
        #pragma unroll
        for (int kt = 0; kt < 2; ++kt){
          bf16x8 a = ld8(&Sg[wave][tp][li][kt*32 + 8*lg]);
          #pragma unroll
          for (int nt = 0; nt < 3; ++nt) hl[nt] = MFMA16(a, lwtF[nt][kt], hl[nt]);
        }
        #pragma unroll
        for (int nt = 0; nt < 3; ++nt){
          u16x4 w;
          #pragma unroll
          for (int r = 0; r < 4; ++r) w[r] = f2bf(hl[nt][r]);
          *(u16x4*)&hlT[nt*16 + li][t*16 + 4*lg] = w;
        }
      }
    }
    __syncthreads();   // hlT complete for next iteration
  }

  // write back h from registers (rows < 196; pad rows/cols already zero)
  #pragma unroll
  for (int tp = 0; tp < 2; ++tp){
    if (tp < ntile){
      const int t = tt[tp];
      #pragma unroll
      for (int nt = 0; nt < 3; ++nt)
        #pragma unroll
        for (int r = 0; r < 4; ++r){
          int row = t*16 + 4*lg + r;
          if (row < NS)
            hrow[(size_t)row*EP + nt*16 + li] = f2bf(hr[tp][nt][r]);
        }
    }
  }
}

// ---------------- output GEMM ----------------
__global__ __launch_bounds__(256) void k_out(const uint16_t* __restrict__ h_b,
    const uint16_t* __restrict__ ow_b, const float* __restrict__ obv,
    float* __restrict__ out){
  const int wave = threadIdx.x >> 6, lane = threadIdx.x & 63;
  const int lg = lane >> 4, li = lane & 15;
  const int m0 = blockIdx.x * 64 + wave * 16;
  const int m = m0 + li;
  const int b = m / NS, si = m - b*NS;
  f32x4 acc[24];
  #pragma unroll
  for (int i = 0; i < 24; ++i) acc[i] = (f32x4)0.0f;
  for (int kt = 0; kt < 12; ++kt){
    int ks = kt*32 + 8*lg;
    int hh = ks / NEH, f = ks - hh*NEH;
    bf16x8 a = ld8(h_b + ((size_t)(b*NH + hh)*SP + si)*EP + f);
    #pragma unroll
    for (int nt = 0; nt < 24; ++nt){
      bf16x8 bb = ld8(ow_b + (size_t)(nt*16 + li)*NF + kt*32 + 8*lg);
      acc[nt] = MFMA16(a, bb, acc[nt]);
    }
  }
  #pragma unroll
  for (int nt = 0; nt < 24; ++nt){
    float bias = obv[nt*16 + li];
    #pragma unroll
    for (int r = 0; r < 4; ++r)
      out[(size_t)(m0 + 4*lg + r)*NF + nt*16 + li] = acc[nt][r] + bias;
  }
}

// ---------------- launch ----------------
extern "C" void kernel_launch(void* const* d_in, const int* in_sizes, int n_in,
                              void* d_out, int out_size, void* d_ws, size_t ws_size,
                              hipStream_t stream){
  const float* x   = (const float*)d_in[0];
  const float* h0  = (const float*)d_in[1];
  const float* ew  = (const float*)d_in[2];
  const float* eb  = (const float*)d_in[3];
  const float* lw  = (const float*)d_in[4];
  const float* gw  = (const float*)d_in[5];
  const float* ow  = (const float*)d_in[6];
  const float* obv = (const float*)d_in[7];
  float* out = (float*)d_out;

  char* w = (char*)d_ws;
  size_t o_inp = 0;
  size_t o_hb  = o_inp + (size_t)NBH*NT*64*12*2;   // inp_fm: 40.9 MB
  size_t o_gw  = o_hb  + (size_t)NBH*SP*EP*2;      // h_b:    58.7 MB
  size_t o_gwt = o_gw  + (size_t)NH*SP*SP*2;
  size_t o_lw  = o_gwt + (size_t)NH*SP*SP*2;
  size_t o_lwt = o_lw  + (size_t)EP*EP*2;
  size_t o_ew  = o_lwt + (size_t)EP*EP*2;
  size_t o_ow  = o_ew  + (size_t)NF*NF*2;
  size_t total = o_ow  + (size_t)NF*NF*2;
  if (ws_size < total) return;

  uint16_t* inp_fm = (uint16_t*)(w + o_inp);
  uint16_t* h_b    = (uint16_t*)(w + o_hb);
  uint16_t* gw_b   = (uint16_t*)(w + o_gw);
  uint16_t* gwt_b  = (uint16_t*)(w + o_gwt);
  uint16_t* lw_b   = (uint16_t*)(w + o_lw);
  uint16_t* lwt_b  = (uint16_t*)(w + o_lwt);
  uint16_t* ew_b   = (uint16_t*)(w + o_ew);
  uint16_t* ow_b   = (uint16_t*)(w + o_ow);

  k_prep_gw<<<(NH*SP*SP + 255)/256, 256, 0, stream>>>(gw, gw_b, gwt_b);
  k_prep_small<<<(NF*NF + 255)/256, 256, 0, stream>>>(lw, ew, ow, lw_b, lwt_b, ew_b, ow_b);
  k_prep_h<<<(NBH*SP + 255)/256, 256, 0, stream>>>(h0, h_b);
  k_embed<<<NBS/64, 256, 0, stream>>>(x, ew_b, eb, inp_fm);
  k_main<<<NBH, 512, 0, stream>>>(gw_b, gwt_b, lw_b, lwt_b, inp_fm, h_b);
  k_out<<<NBS/64, 256, 0, stream>>>(h_b, ow_b, obv, out);
}

// Round 6
// 846.072 us; speedup vs baseline: 2.0105x; 1.3069x over previous
//
#include <hip/hip_runtime.h>
#include <stdint.h>

#define NB   256      // batch
#define NS   196      // seq len (= hidden seq)
#define NF   384      // in/out features
#define NH   8        // heads
#define NEH  48       // per-head dim
#define NIT  10
#define SP   224      // padded seq (14 tiles of 16)
#define EP   64       // padded per-head dim (K padding; N uses exactly 48)
#define NBH  2048     // NB*NH
#define NBS  50176    // NB*NS
#define NT   13       // inp tiles (rows<196 only)

using f32x4  = __attribute__((ext_vector_type(4))) float;
using u16x8  = __attribute__((ext_vector_type(8))) uint16_t;
using u16x4  = __attribute__((ext_vector_type(4))) uint16_t;
using bf16x8 = __attribute__((ext_vector_type(8))) __bf16;

static __device__ __forceinline__ float bf2f(uint16_t u){
  union { uint32_t u32; float f; } c; c.u32 = (uint32_t)u << 16; return c.f;
}
// RTNE f32->bf16 via compiler cast (emits v_cvt_pk_bf16_f32; ~5x fewer VALU
// ops than the manual add/shift rounding)
static __device__ __forceinline__ uint16_t f2bf(float f){
  __bf16 h = (__bf16)f;
  return __builtin_bit_cast(uint16_t, h);
}
// fast reciprocal (v_rcp_f32, ~1ulp -- far below bf16 quantization)
static __device__ __forceinline__ float frcp(float f){
  return __builtin_amdgcn_rcpf(f);
}
static __device__ __forceinline__ bf16x8 ld8(const uint16_t* p){
  return __builtin_bit_cast(bf16x8, *(const u16x8*)p);
}
// in-wave LDS write->read ordering (through per-wave private staging)
static __device__ __forceinline__ void lds_fence(){
  asm volatile("s_waitcnt lgkmcnt(0)" ::: "memory");
}
#define MFMA16(a,b,c) __builtin_amdgcn_mfma_f32_16x16x32_bf16((a),(b),(c),0,0,0)

// ---------------- prep kernels ----------------

__global__ void k_prep_gw(const float* __restrict__ gw, uint16_t* __restrict__ gw_b,
                          uint16_t* __restrict__ gwt_b){
  int idx = blockIdx.x * 256 + threadIdx.x;
  if (idx >= NH*SP*SP) return;
  int h = idx / (SP*SP);
  int r = (idx / SP) % SP;   // o
  int c = idx % SP;          // i
  float v = (r < NS && c < NS) ? gw[((size_t)h*NS + r)*NS + c] : 0.f;
  uint16_t bv = f2bf(v);
  gw_b[idx] = bv;
  gwt_b[((size_t)h*SP + c)*SP + r] = bv;
}

__global__ void k_prep_small(const float* __restrict__ lw, const float* __restrict__ ew,
                             const float* __restrict__ ow,
                             uint16_t* __restrict__ lw_b, uint16_t* __restrict__ lwt_b,
                             uint16_t* __restrict__ ew_b, uint16_t* __restrict__ ow_b){
  int idx = blockIdx.x * 256 + threadIdx.x;
  if (idx < EP*EP){
    int f = idx >> 6, e = idx & 63;
    float v = (f < NEH && e < NEH) ? lw[f*NEH + e] : 0.f;
    uint16_t bv = f2bf(v);
    lw_b[f*EP + e] = bv;     // [f][e]
    lwt_b[e*EP + f] = bv;    // [e][f]
  }
  if (idx < NF*NF){
    ew_b[idx] = f2bf(ew[idx]);
    ow_b[idx] = f2bf(ow[idx]);
  }
}

__global__ void k_prep_h(const float* __restrict__ h0, uint16_t* __restrict__ h_b){
  int idx = blockIdx.x * 256 + threadIdx.x;
  if (idx >= NBH*SP) return;
  int bh = idx / SP, o = idx % SP;
  int b = bh >> 3, h = bh & 7;
  uint16_t* dst = h_b + (size_t)idx * EP;
  if (o < NS){
    const float* src = h0 + (((size_t)(b*NS + o))*NH + h)*NEH;
    float s = 0.f;
    float v[48];
    #pragma unroll
    for (int j = 0; j < NEH; ++j){ v[j] = src[j]; s += fabsf(v[j]); }
    s = fmaxf(s, 1e-12f);
    float inv = 1.f / s;
    #pragma unroll
    for (int j = 0; j < NEH; ++j) dst[j] = f2bf(v[j] * inv);
    #pragma unroll
    for (int j = NEH; j < EP; ++j) dst[j] = 0;
  } else {
    #pragma unroll
    for (int j = 0; j < EP; ++j) dst[j] = 0;
  }
}

// ---------------- embed GEMM + input prep ----------------
// xe = clamp(x @ ew^T + b, 1e-6); inp = xe/rowsum48, written FRAGMENT-MAJOR:
// inp_fm[bh][t][lane][slot], lane=(wi>>2)*16+li, slot=j*4+(wi&3), wi=si%16
__global__ __launch_bounds__(256) void k_embed(const float* __restrict__ x,
    const uint16_t* __restrict__ ew_b, const float* __restrict__ eb,
    uint16_t* __restrict__ inp_fm){
  const int wave = threadIdx.x >> 6, lane = threadIdx.x & 63;
  const int lg = lane >> 4, li = lane & 15;
  const int m0 = blockIdx.x * 64 + wave * 16;
  f32x4 acc[24];
  #pragma unroll
  for (int i = 0; i < 24; ++i) acc[i] = (f32x4)0.0f;
  const float* ap = x + (size_t)(m0 + li) * NF + 8*lg;
  for (int kt = 0; kt < 12; ++kt){
    f32x4 a0 = *(const f32x4*)(ap + kt*32);
    f32x4 a1 = *(const f32x4*)(ap + kt*32 + 4);
    u16x8 au;
    #pragma unroll
    for (int j = 0; j < 4; ++j){ au[j] = f2bf(a0[j]); au[j+4] = f2bf(a1[j]); }
    bf16x8 a = __builtin_bit_cast(bf16x8, au);
    #pragma unroll
    for (int nt = 0; nt < 24; ++nt){
      bf16x8 b = ld8(ew_b + (size_t)(nt*16 + li)*NF + kt*32 + 8*lg);
      acc[nt] = MFMA16(a, b, acc[nt]);
    }
  }
  #pragma unroll
  for (int hh = 0; hh < 8; ++hh){
    float xec[3][4];
    float s[4] = {0.f, 0.f, 0.f, 0.f};
    #pragma unroll
    for (int j = 0; j < 3; ++j){
      int nt = hh*3 + j;
      float bias = eb[nt*16 + li];
      #pragma unroll
      for (int r = 0; r < 4; ++r){
        float v = fmaxf(acc[nt][r] + bias, 1e-6f);
        xec[j][r] = v; s[r] += v;
      }
    }
    #pragma unroll
    for (int r = 0; r < 4; ++r){
      float t = s[r];
      t += __shfl_xor(t, 1); t += __shfl_xor(t, 2);
      t += __shfl_xor(t, 4); t += __shfl_xor(t, 8);
      s[r] = t;
    }
    #pragma unroll
    for (int r = 0; r < 4; ++r){
      int m = m0 + 4*lg + r;
      int b = m / NS, si = m - b*NS;
      int t = si >> 4, wi = si & 15;
      int lanep = (wi >> 2)*16 + li;
      float inv = frcp(s[r]);
      size_t base = ((size_t)((b*NH + hh)*NT + t)*64 + lanep)*12 + (wi & 3);
      #pragma unroll
      for (int j = 0; j < 3; ++j)
        inp_fm[base + j*4] = f2bf(xec[j][r] * inv);
    }
  }
}

// ---------------- main NNMF fixed-point kernel ----------------
// One block per (b,h). 7 waves x 2 tiles = 14 tiles (incl. zero pad tile 13)
// -- perfectly balanced. rec = gwT x (h x lw) via maintained hl. 2 barriers
// per iteration. h fp32 in regs. Sg row stride 72 elems = 144 B = 9 x 16 B:
// every staged ds_read_b128 is 16B-aligned and rows spread odd across bank
// groups (r5's stride 68 made odd rows 8-mod-16 -> misaligned b128 = the
// bank-conflict counter blowup).
__global__ __launch_bounds__(448) void k_main(
    const uint16_t* __restrict__ gw_b,   // [H][SP][SP] (o,i)
    const uint16_t* __restrict__ gwt_b,  // [H][SP][SP] (i,o)
    const uint16_t* __restrict__ lw_b,   // [EP][EP] (f,e)
    const uint16_t* __restrict__ lwt_b,  // [EP][EP] (e,f)
    const uint16_t* __restrict__ inp_fm, // [BH][13][64][12]
    uint16_t* __restrict__ h_b)          // [BH][SP][EP]
{
  __shared__ __align__(16) uint16_t hlT[48][232];      // (h x lw)^T  [e][o]
  __shared__ __align__(16) uint16_t t2T[48][232];      // t2^T        [f][i]
  __shared__ __align__(16) uint16_t Sg[7][2][16][72];  // per-wave staging

  const int bh = blockIdx.x;
  const int hh = bh & 7;
  const int tid = threadIdx.x;
  const int wave = tid >> 6;
  const int lane = tid & 63;
  const int lg = lane >> 4;
  const int li = lane & 15;
  const int tt[2] = {wave, wave + 7};

  // zero staging K-pad cols 48..63 (never rewritten; kt=1 A-frag reads them)
  {
    u16x4 z = {0,0,0,0};
    *(u16x4*)&Sg[wave][0][li][48 + 4*lg] = z;
    *(u16x4*)&Sg[wave][1][li][48 + 4*lg] = z;
  }

  // local-weight B-fragments (constant across iterations)
  bf16x8 lwtF[3][2], lwF[3][2];
  #pragma unroll
  for (int nt = 0; nt < 3; ++nt)
    #pragma unroll
    for (int kt = 0; kt < 2; ++kt){
      lwtF[nt][kt] = ld8(lwt_b + (size_t)(nt*16 + li)*EP + kt*32 + 8*lg); // B[k=f][n=e]
      lwF [nt][kt] = ld8(lw_b  + (size_t)(nt*16 + li)*EP + kt*32 + 8*lg); // B[k=e][n=f]
    }

  // load h into fp32 regs (D-layout: row=t*16+4lg+r, col=nt*16+li) and stage
  uint16_t* __restrict__ hrow = h_b + (size_t)bh * SP * EP;
  float hr[2][3][4];
  #pragma unroll
  for (int tp = 0; tp < 2; ++tp){
    const int t = tt[tp];
    #pragma unroll
    for (int nt = 0; nt < 3; ++nt)
      #pragma unroll
      for (int r = 0; r < 4; ++r){
        uint16_t u = hrow[(size_t)(t*16 + 4*lg + r)*EP + nt*16 + li];
        hr[tp][nt][r] = bf2f(u);
        Sg[wave][tp][4*lg + r][nt*16 + li] = u;
      }
  }
  lds_fence();
  // initial hl = h x lw -> hlT
  #pragma unroll
  for (int tp = 0; tp < 2; ++tp){
    const int t = tt[tp];
    f32x4 hl[3];
    #pragma unroll
    for (int i = 0; i < 3; ++i) hl[i] = (f32x4)0.0f;
    #pragma unroll
    for (int kt = 0; kt < 2; ++kt){
      bf16x8 a = ld8(&Sg[wave][tp][li][kt*32 + 8*lg]);
      #pragma unroll
      for (int nt = 0; nt < 3; ++nt) hl[nt] = MFMA16(a, lwtF[nt][kt], hl[nt]);
    }
    #pragma unroll
    for (int nt = 0; nt < 3; ++nt){
      u16x4 w;
      #pragma unroll
      for (int r = 0; r < 4; ++r) w[r] = f2bf(hl[nt][r]);
      *(u16x4*)&hlT[nt*16 + li][t*16 + 4*lg] = w;
    }
  }

  const uint16_t* __restrict__ gwh  = gw_b  + (size_t)hh * SP * SP;
  const uint16_t* __restrict__ gwth = gwt_b + (size_t)hh * SP * SP;
  __syncthreads();   // hlT ready

  for (int it = 0; it < NIT; ++it){
    // ---- phase B: rec = gwt x hlT; ratio; t2 = ratio x lw -> t2T
    #pragma unroll
    for (int tp = 0; tp < 2; ++tp){
      const int t = tt[tp];
      // prefetch inp fragment (hidden under rec GEMM); tile 13 has no inp
      const uint16_t* ipp = inp_fm +
          ((size_t)(bh*NT + (t < NT ? t : NT-1))*64 + lg*16 + li)*12;
      u16x4 ip0 = *(const u16x4*)(ipp);
      u16x4 ip1 = *(const u16x4*)(ipp + 4);
      u16x4 ip2 = *(const u16x4*)(ipp + 8);
      // rec[i][e] = sum_o gwt[i][o] * hl[o][e]
      f32x4 rec[3];
      #pragma unroll
      for (int i = 0; i < 3; ++i) rec[i] = (f32x4)0.0f;
      const uint16_t* gA = gwth + (size_t)(t*16 + li)*SP + 8*lg;
      #pragma unroll
      for (int kt = 0; kt < 7; ++kt){
        bf16x8 a = ld8(gA + kt*32);
        #pragma unroll
        for (int nt = 0; nt < 3; ++nt)
          rec[nt] = MFMA16(a, ld8(&hlT[nt*16 + li][kt*32 + 8*lg]), rec[nt]);
      }
      // ratio = inp * rowsum(clip(rec)) * rcp(clip(rec)), staged to Sg
      float s[4] = {0.f,0.f,0.f,0.f};
      float rv[3][4];
      #pragma unroll
      for (int nt = 0; nt < 3; ++nt)
        #pragma unroll
        for (int r = 0; r < 4; ++r){
          float v = fmaxf(rec[nt][r], 1e-6f);
          rv[nt][r] = v; s[r] += v;
        }
      #pragma unroll
      for (int r = 0; r < 4; ++r){
        float v = s[r];
        v += __shfl_xor(v, 1); v += __shfl_xor(v, 2);
        v += __shfl_xor(v, 4); v += __shfl_xor(v, 8);
        s[r] = v;
      }
      #pragma unroll
      for (int r = 0; r < 4; ++r){
        Sg[wave][tp][4*lg + r][ 0 + li] = f2bf(bf2f(ip0[r]) * s[r] * frcp(rv[0][r]));
        Sg[wave][tp][4*lg + r][16 + li] = f2bf(bf2f(ip1[r]) * s[r] * frcp(rv[1][r]));
        Sg[wave][tp][4*lg + r][32 + li] = f2bf(bf2f(ip2[r]) * s[r] * frcp(rv[2][r]));
      }
      lds_fence();
      // t2[i][f] = sum_e ratio[i][e] * lw[f][e] -> t2T
      f32x4 t2[3];
      #pragma unroll
      for (int i = 0; i < 3; ++i) t2[i] = (f32x4)0.0f;
      #pragma unroll
      for (int kt = 0; kt < 2; ++kt){
        bf16x8 a = ld8(&Sg[wave][tp][li][kt*32 + 8*lg]);
        #pragma unroll
        for (int nt = 0; nt < 3; ++nt) t2[nt] = MFMA16(a, lwF[nt][kt], t2[nt]);
      }
      #pragma unroll
      for (int nt = 0; nt < 3; ++nt){
        u16x4 w;
        #pragma unroll
        for (int r = 0; r < 4; ++r) w[r] = f2bf(t2[nt][r]);
        *(u16x4*)&t2T[nt*16 + li][t*16 + 4*lg] = w;
      }
    }
    __syncthreads();   // t2T complete

    // ---- phase C: hu = gw x t2T; h = norm(clip(h*hu)); hl = h x lw -> hlT
    #pragma unroll
    for (int tp = 0; tp < 2; ++tp){
      const int t = tt[tp];
      f32x4 hu[3];
      #pragma unroll
      for (int i = 0; i < 3; ++i) hu[i] = (f32x4)0.0f;
      const uint16_t* gA = gwh + (size_t)(t*16 + li)*SP + 8*lg;
      #pragma unroll
      for (int kt = 0; kt < 7; ++kt){
        bf16x8 a = ld8(gA + kt*32);
        #pragma unroll
        for (int nt = 0; nt < 3; ++nt)
          hu[nt] = MFMA16(a, ld8(&t2T[nt*16 + li][kt*32 + 8*lg]), hu[nt]);
      }
      float s[4] = {0.f,0.f,0.f,0.f};
      #pragma unroll
      for (int nt = 0; nt < 3; ++nt)
        #pragma unroll
        for (int r = 0; r < 4; ++r){
          float v = fmaxf(hr[tp][nt][r] * hu[nt][r], 1e-6f);
          hr[tp][nt][r] = v; s[r] += v;
        }
      #pragma unroll
      for (int r = 0; r < 4; ++r){
        float v = s[r];
        v += __shfl_xor(v, 1); v += __shfl_xor(v, 2);
        v += __shfl_xor(v, 4); v += __shfl_xor(v, 8);
        s[r] = frcp(v);
      }
      #pragma unroll
      for (int nt = 0; nt < 3; ++nt)
        #pragma unroll
        for (int r = 0; r < 4; ++r){
          hr[tp][nt][r] *= s[r];
          Sg[wave][tp][4*lg + r][nt*16 + li] = f2bf(hr[tp][nt][r]);
        }
      lds_fence();
      f32x4 hl[3];
      #pragma unroll
      for (int i = 0; i < 3; ++i) hl[i] = (f32x4)0.0f;
      #pragma unroll
      for (int kt = 0; kt < 2; ++kt){
        bf16x8 a = ld8(&Sg[wave][tp][li][kt*32 + 8*lg]);
        #pragma unroll
        for (int nt = 0; nt < 3; ++nt) hl[nt] = MFMA16(a, lwtF[nt][kt], hl[nt]);
      }
      #pragma unroll
      for (int nt = 0; nt < 3; ++nt){
        u16x4 w;
        #pragma unroll
        for (int r = 0; r < 4; ++r) w[r] = f2bf(hl[nt][r]);
        *(u16x4*)&hlT[nt*16 + li][t*16 + 4*lg] = w;
      }
    }
    __syncthreads();   // hlT complete for next iteration
  }

  // write back h from registers (rows < 196; pad rows/cols already zero)
  #pragma unroll
  for (int tp = 0; tp < 2; ++tp){
    const int t = tt[tp];
    #pragma unroll
    for (int nt = 0; nt < 3; ++nt)
      #pragma unroll
      for (int r = 0; r < 4; ++r){
        int row = t*16 + 4*lg + r;
        if (row < NS)
          hrow[(size_t)row*EP + nt*16 + li] = f2bf(hr[tp][nt][r]);
      }
  }
}

// ---------------- output GEMM ----------------
__global__ __launch_bounds__(256) void k_out(const uint16_t* __restrict__ h_b,
    const uint16_t* __restrict__ ow_b, const float* __restrict__ obv,
    float* __restrict__ out){
  const int wave = threadIdx.x >> 6, lane = threadIdx.x & 63;
  const int lg = lane >> 4, li = lane & 15;
  const int m0 = blockIdx.x * 64 + wave * 16;
  const int m = m0 + li;
  const int b = m / NS, si = m - b*NS;
  f32x4 acc[24];
  #pragma unroll
  for (int i = 0; i < 24; ++i) acc[i] = (f32x4)0.0f;
  for (int kt = 0; kt < 12; ++kt){
    int ks = kt*32 + 8*lg;
    int hh = ks / NEH, f = ks - hh*NEH;
    bf16x8 a = ld8(h_b + ((size_t)(b*NH + hh)*SP + si)*EP + f);
    #pragma unroll
    for (int nt = 0; nt < 24; ++nt){
      bf16x8 bb = ld8(ow_b + (size_t)(nt*16 + li)*NF + kt*32 + 8*lg);
      acc[nt] = MFMA16(a, bb, acc[nt]);
    }
  }
  #pragma unroll
  for (int nt = 0; nt < 24; ++nt){
    float bias = obv[nt*16 + li];
    #pragma unroll
    for (int r = 0; r < 4; ++r)
      out[(size_t)(m0 + 4*lg + r)*NF + nt*16 + li] = acc[nt][r] + bias;
  }
}

// ---------------- launch ----------------
extern "C" void kernel_launch(void* const* d_in, const int* in_sizes, int n_in,
                              void* d_out, int out_size, void* d_ws, size_t ws_size,
                              hipStream_t stream){
  const float* x   = (const float*)d_in[0];
  const float* h0  = (const float*)d_in[1];
  const float* ew  = (const float*)d_in[2];
  const float* eb  = (const float*)d_in[3];
  const float* lw  = (const float*)d_in[4];
  const float* gw  = (const float*)d_in[5];
  const float* ow  = (const float*)d_in[6];
  const float* obv = (const float*)d_in[7];
  float* out = (float*)d_out;

  char* w = (char*)d_ws;
  size_t o_inp = 0;
  size_t o_hb  = o_inp + (size_t)NBH*NT*64*12*2;   // inp_fm: 40.9 MB
  size_t o_gw  = o_hb  + (size_t)NBH*SP*EP*2;      // h_b:    58.7 MB
  size_t o_gwt = o_gw  + (size_t)NH*SP*SP*2;
  size_t o_lw  = o_gwt + (size_t)NH*SP*SP*2;
  size_t o_lwt = o_lw  + (size_t)EP*EP*2;
  size_t o_ew  = o_lwt + (size_t)EP*EP*2;
  size_t o_ow  = o_ew  + (size_t)NF*NF*2;
  size_t total = o_ow  + (size_t)NF*NF*2;
  if (ws_size < total) return;

  uint16_t* inp_fm = (uint16_t*)(w + o_inp);
  uint16_t* h_b    = (uint16_t*)(w + o_hb);
  uint16_t* gw_b   = (uint16_t*)(w + o_gw);
  uint16_t* gwt_b  = (uint16_t*)(w + o_gwt);
  uint16_t* lw_b   = (uint16_t*)(w + o_lw);
  uint16_t* lwt_b  = (uint16_t*)(w + o_lwt);
  uint16_t* ew_b   = (uint16_t*)(w + o_ew);
  uint16_t* ow_b   = (uint16_t*)(w + o_ow);

  k_prep_gw<<<(NH*SP*SP + 255)/256, 256, 0, stream>>>(gw, gw_b, gwt_b);
  k_prep_small<<<(NF*NF + 255)/256, 256, 0, stream>>>(lw, ew, ow, lw_b, lwt_b, ew_b, ow_b);
  k_prep_h<<<(NBH*SP + 255)/256, 256, 0, stream>>>(h0, h_b);
  k_embed<<<NBS/64, 256, 0, stream>>>(x, ew_b, eb, inp_fm);
  k_main<<<NBH, 448, 0, stream>>>(gw_b, gwt_b, lw_b, lwt_b, inp_fm, h_b);
  k_out<<<NBS/64, 256, 0, stream>>>(h_b, ow_b, obv, out);
}

// Round 7
// 764.907 us; speedup vs baseline: 2.2238x; 1.1061x over previous
//
#include <hip/hip_runtime.h>
#include <stdint.h>

#define NB   256      // batch
#define NS   196      // seq len (= hidden seq)
#define NF   384      // in/out features
#define NH   8        // heads
#define NEH  48       // per-head dim
#define NIT  10
#define SP   224      // padded seq (14 tiles of 16)
#define EP   64       // padded per-head dim (K padding; N uses exactly 48)
#define NBH  2048     // NB*NH
#define NBS  50176    // NB*NS
#define NT   13       // inp tiles (rows<196 only)

using f32x4  = __attribute__((ext_vector_type(4))) float;
using u16x8  = __attribute__((ext_vector_type(8))) uint16_t;
using u16x4  = __attribute__((ext_vector_type(4))) uint16_t;
using bf16x8 = __attribute__((ext_vector_type(8))) __bf16;

static __device__ __forceinline__ float bf2f(uint16_t u){
  union { uint32_t u32; float f; } c; c.u32 = (uint32_t)u << 16; return c.f;
}
static __device__ __forceinline__ uint16_t f2bf(float f){
  __bf16 h = (__bf16)f;
  return __builtin_bit_cast(uint16_t, h);
}
static __device__ __forceinline__ float frcp(float f){
  return __builtin_amdgcn_rcpf(f);
}
static __device__ __forceinline__ bf16x8 ld8(const uint16_t* p){
  return __builtin_bit_cast(bf16x8, *(const u16x8*)p);
}
static __device__ __forceinline__ void lds_fence(){
  asm volatile("s_waitcnt lgkmcnt(0)" ::: "memory");
}
// 16-lane sum via DPP (replaces 4 ds_bpermute shuffles with 4 VALU adds):
// xor1 = quad_perm(1,0,3,2)=0xB1; xor2 = quad_perm(2,3,0,1)=0x4E;
// then row_half_mirror(0x141) + row_mirror(0x140) pair the quad/half sums.
static __device__ __forceinline__ float dpp_add16(float x){
  int v = __builtin_bit_cast(int, x);
  x += __builtin_bit_cast(float, __builtin_amdgcn_update_dpp(0, v, 0xB1, 0xF, 0xF, false));
  v = __builtin_bit_cast(int, x);
  x += __builtin_bit_cast(float, __builtin_amdgcn_update_dpp(0, v, 0x4E, 0xF, 0xF, false));
  v = __builtin_bit_cast(int, x);
  x += __builtin_bit_cast(float, __builtin_amdgcn_update_dpp(0, v, 0x141, 0xF, 0xF, false));
  v = __builtin_bit_cast(int, x);
  x += __builtin_bit_cast(float, __builtin_amdgcn_update_dpp(0, v, 0x140, 0xF, 0xF, false));
  return x;
}
#define MFMA16(a,b,c) __builtin_amdgcn_mfma_f32_16x16x32_bf16((a),(b),(c),0,0,0)

// ---------------- prep kernels ----------------

__global__ void k_prep_gw(const float* __restrict__ gw, uint16_t* __restrict__ gw_b,
                          uint16_t* __restrict__ gwt_b){
  int idx = blockIdx.x * 256 + threadIdx.x;
  if (idx >= NH*SP*SP) return;
  int h = idx / (SP*SP);
  int r = (idx / SP) % SP;   // o
  int c = idx % SP;          // i
  float v = (r < NS && c < NS) ? gw[((size_t)h*NS + r)*NS + c] : 0.f;
  uint16_t bv = f2bf(v);
  gw_b[idx] = bv;
  gwt_b[((size_t)h*SP + c)*SP + r] = bv;
}

__global__ void k_prep_small(const float* __restrict__ lw, const float* __restrict__ ew,
                             const float* __restrict__ ow,
                             uint16_t* __restrict__ lw_b, uint16_t* __restrict__ lwt_b,
                             uint16_t* __restrict__ ew_b, uint16_t* __restrict__ ow_b){
  int idx = blockIdx.x * 256 + threadIdx.x;
  if (idx < EP*EP){
    int f = idx >> 6, e = idx & 63;
    float v = (f < NEH && e < NEH) ? lw[f*NEH + e] : 0.f;
    uint16_t bv = f2bf(v);
    lw_b[f*EP + e] = bv;     // [f][e]
    lwt_b[e*EP + f] = bv;    // [e][f]
  }
  if (idx < NF*NF){
    ew_b[idx] = f2bf(ew[idx]);
    ow_b[idx] = f2bf(ow[idx]);
  }
}

__global__ void k_prep_h(const float* __restrict__ h0, uint16_t* __restrict__ h_b){
  int idx = blockIdx.x * 256 + threadIdx.x;
  if (idx >= NBH*SP) return;
  int bh = idx / SP, o = idx % SP;
  int b = bh >> 3, h = bh & 7;
  uint16_t* dst = h_b + (size_t)idx * EP;
  if (o < NS){
    const float* src = h0 + (((size_t)(b*NS + o))*NH + h)*NEH;
    float s = 0.f;
    float v[48];
    #pragma unroll
    for (int j = 0; j < NEH; ++j){ v[j] = src[j]; s += fabsf(v[j]); }
    s = fmaxf(s, 1e-12f);
    float inv = 1.f / s;
    #pragma unroll
    for (int j = 0; j < NEH; ++j) dst[j] = f2bf(v[j] * inv);
    #pragma unroll
    for (int j = NEH; j < EP; ++j) dst[j] = 0;
  } else {
    #pragma unroll
    for (int j = 0; j < EP; ++j) dst[j] = 0;
  }
}

// ---------------- embed GEMM + input prep ----------------
// 8 waves: wave = mt*2+nh; each wave: 16 rows x 192 cols (12 nt). acc = 48
// VGPR (vs 96 at 4-wave) -> ~2x occupancy for latency hiding.
// inp written FRAGMENT-MAJOR: inp_fm[bh][t][lane][slot],
// lane=(wi>>2)*16+li, slot=j*4+(wi&3), wi=si%16
__global__ __launch_bounds__(512) void k_embed(const float* __restrict__ x,
    const uint16_t* __restrict__ ew_b, const float* __restrict__ eb,
    uint16_t* __restrict__ inp_fm){
  const int wave = threadIdx.x >> 6, lane = threadIdx.x & 63;
  const int lg = lane >> 4, li = lane & 15;
  const int mt = wave >> 1, nh = wave & 1;
  const int m0 = blockIdx.x * 64 + mt * 16;
  f32x4 acc[12];
  #pragma unroll
  for (int i = 0; i < 12; ++i) acc[i] = (f32x4)0.0f;
  const float* ap = x + (size_t)(m0 + li) * NF + 8*lg;
  for (int kt = 0; kt < 12; ++kt){
    f32x4 a0 = *(const f32x4*)(ap + kt*32);
    f32x4 a1 = *(const f32x4*)(ap + kt*32 + 4);
    u16x8 au;
    #pragma unroll
    for (int j = 0; j < 4; ++j){ au[j] = f2bf(a0[j]); au[j+4] = f2bf(a1[j]); }
    bf16x8 a = __builtin_bit_cast(bf16x8, au);
    #pragma unroll
    for (int nt = 0; nt < 12; ++nt){
      bf16x8 b = ld8(ew_b + (size_t)((nh*12 + nt)*16 + li)*NF + kt*32 + 8*lg);
      acc[nt] = MFMA16(a, b, acc[nt]);
    }
  }
  // epilogue: 4 heads per wave (hh = nh*4 + hl), 3 nt each
  #pragma unroll
  for (int hl = 0; hl < 4; ++hl){
    int hh = nh*4 + hl;
    float xec[3][4];
    float s[4] = {0.f, 0.f, 0.f, 0.f};
    #pragma unroll
    for (int j = 0; j < 3; ++j){
      int nt = hl*3 + j;
      float bias = eb[(nh*12 + nt)*16 + li];
      #pragma unroll
      for (int r = 0; r < 4; ++r){
        float v = fmaxf(acc[nt][r] + bias, 1e-6f);
        xec[j][r] = v; s[r] += v;
      }
    }
    #pragma unroll
    for (int r = 0; r < 4; ++r) s[r] = dpp_add16(s[r]);
    #pragma unroll
    for (int r = 0; r < 4; ++r){
      int m = m0 + 4*lg + r;
      int b = m / NS, si = m - b*NS;
      int t = si >> 4, wi = si & 15;
      int lanep = (wi >> 2)*16 + li;
      float inv = frcp(s[r]);
      size_t base = ((size_t)((b*NH + hh)*NT + t)*64 + lanep)*12 + (wi & 3);
      #pragma unroll
      for (int j = 0; j < 3; ++j)
        inp_fm[base + j*4] = f2bf(xec[j][r] * inv);
    }
  }
}

// ---------------- main NNMF fixed-point kernel ----------------
// One block per (b,h). 7 waves x 2 tiles = 14 tiles (incl. zero pad tile 13).
// rec = gwT x (h x lw) via maintained hl. 2 barriers + 2 in-wave fences/iter.
// h fp32 in regs; inp bf16 in regs (iteration-invariant, loaded once).
// Row sums via DPP (VALU), not ds_bpermute. Tiles interleaved per phase:
// both GEMMs issued before the reduce/stage sections, one shared fence.
__global__ __launch_bounds__(448) void k_main(
    const uint16_t* __restrict__ gw_b,   // [H][SP][SP] (o,i)
    const uint16_t* __restrict__ gwt_b,  // [H][SP][SP] (i,o)
    const uint16_t* __restrict__ lw_b,   // [EP][EP] (f,e)
    const uint16_t* __restrict__ lwt_b,  // [EP][EP] (e,f)
    const uint16_t* __restrict__ inp_fm, // [BH][13][64][12]
    uint16_t* __restrict__ h_b)          // [BH][SP][EP]
{
  __shared__ __align__(16) uint16_t hlT[48][232];      // (h x lw)^T  [e][o]
  __shared__ __align__(16) uint16_t t2T[48][232];      // t2^T        [f][i]
  __shared__ __align__(16) uint16_t Sg[7][2][16][72];  // per-wave staging

  const int bh = blockIdx.x;
  const int hh = bh & 7;
  const int tid = threadIdx.x;
  const int wave = tid >> 6;
  const int lane = tid & 63;
  const int lg = lane >> 4;
  const int li = lane & 15;
  const int tt[2] = {wave, wave + 7};

  // zero staging K-pad cols 48..63 (never rewritten; kt=1 A-frag reads them)
  {
    u16x4 z = {0,0,0,0};
    *(u16x4*)&Sg[wave][0][li][48 + 4*lg] = z;
    *(u16x4*)&Sg[wave][1][li][48 + 4*lg] = z;
  }

  // local-weight B-fragments (constant across iterations)
  bf16x8 lwtF[3][2], lwF[3][2];
  #pragma unroll
  for (int nt = 0; nt < 3; ++nt)
    #pragma unroll
    for (int kt = 0; kt < 2; ++kt){
      lwtF[nt][kt] = ld8(lwt_b + (size_t)(nt*16 + li)*EP + kt*32 + 8*lg); // B[k=f][n=e]
      lwF [nt][kt] = ld8(lw_b  + (size_t)(nt*16 + li)*EP + kt*32 + 8*lg); // B[k=e][n=f]
    }

  // persistent inp fragments (iteration-invariant): pad tile 13 -> zeros
  u16x4 ip[2][3];
  #pragma unroll
  for (int tp = 0; tp < 2; ++tp){
    const int t = tt[tp];
    if (t < NT){
      const uint16_t* ipp = inp_fm + ((size_t)(bh*NT + t)*64 + lg*16 + li)*12;
      ip[tp][0] = *(const u16x4*)(ipp);
      ip[tp][1] = *(const u16x4*)(ipp + 4);
      ip[tp][2] = *(const u16x4*)(ipp + 8);
    } else {
      u16x4 z = {0,0,0,0};
      ip[tp][0] = z; ip[tp][1] = z; ip[tp][2] = z;
    }
  }

  // load h into fp32 regs (D-layout: row=t*16+4lg+r, col=nt*16+li) and stage
  uint16_t* __restrict__ hrow = h_b + (size_t)bh * SP * EP;
  float hr[2][3][4];
  #pragma unroll
  for (int tp = 0; tp < 2; ++tp){
    const int t = tt[tp];
    #pragma unroll
    for (int nt = 0; nt < 3; ++nt)
      #pragma unroll
      for (int r = 0; r < 4; ++r){
        uint16_t u = hrow[(size_t)(t*16 + 4*lg + r)*EP + nt*16 + li];
        hr[tp][nt][r] = bf2f(u);
        Sg[wave][tp][4*lg + r][nt*16 + li] = u;
      }
  }
  lds_fence();
  // initial hl = h x lw -> hlT
  #pragma unroll
  for (int tp = 0; tp < 2; ++tp){
    const int t = tt[tp];
    f32x4 hl[3];
    #pragma unroll
    for (int i = 0; i < 3; ++i) hl[i] = (f32x4)0.0f;
    #pragma unroll
    for (int kt = 0; kt < 2; ++kt){
      bf16x8 a = ld8(&Sg[wave][tp][li][kt*32 + 8*lg]);
      #pragma unroll
      for (int nt = 0; nt < 3; ++nt) hl[nt] = MFMA16(a, lwtF[nt][kt], hl[nt]);
    }
    #pragma unroll
    for (int nt = 0; nt < 3; ++nt){
      u16x4 w;
      #pragma unroll
      for (int r = 0; r < 4; ++r) w[r] = f2bf(hl[nt][r]);
      *(u16x4*)&hlT[nt*16 + li][t*16 + 4*lg] = w;
    }
  }

  const uint16_t* __restrict__ gwh  = gw_b  + (size_t)hh * SP * SP;
  const uint16_t* __restrict__ gwth = gwt_b + (size_t)hh * SP * SP;
  __syncthreads();   // hlT ready

  for (int it = 0; it < NIT; ++it){
    // ---- phase B: rec = gwt x hlT (both tiles); ratio; t2 = ratio x lw
    f32x4 rec[2][3];
    #pragma unroll
    for (int tp = 0; tp < 2; ++tp){
      const int t = tt[tp];
      #pragma unroll
      for (int i = 0; i < 3; ++i) rec[tp][i] = (f32x4)0.0f;
      const uint16_t* gA = gwth + (size_t)(t*16 + li)*SP + 8*lg;
      #pragma unroll
      for (int kt = 0; kt < 7; ++kt){
        bf16x8 a = ld8(gA + kt*32);
        #pragma unroll
        for (int nt = 0; nt < 3; ++nt)
          rec[tp][nt] = MFMA16(a, ld8(&hlT[nt*16 + li][kt*32 + 8*lg]), rec[tp][nt]);
      }
    }
    #pragma unroll
    for (int tp = 0; tp < 2; ++tp){
      float s[4] = {0.f,0.f,0.f,0.f};
      float rv[3][4];
      #pragma unroll
      for (int nt = 0; nt < 3; ++nt)
        #pragma unroll
        for (int r = 0; r < 4; ++r){
          float v = fmaxf(rec[tp][nt][r], 1e-6f);
          rv[nt][r] = v; s[r] += v;
        }
      #pragma unroll
      for (int r = 0; r < 4; ++r) s[r] = dpp_add16(s[r]);
      #pragma unroll
      for (int r = 0; r < 4; ++r){
        Sg[wave][tp][4*lg + r][ 0 + li] = f2bf(bf2f(ip[tp][0][r]) * s[r] * frcp(rv[0][r]));
        Sg[wave][tp][4*lg + r][16 + li] = f2bf(bf2f(ip[tp][1][r]) * s[r] * frcp(rv[1][r]));
        Sg[wave][tp][4*lg + r][32 + li] = f2bf(bf2f(ip[tp][2][r]) * s[r] * frcp(rv[2][r]));
      }
    }
    lds_fence();
    #pragma unroll
    for (int tp = 0; tp < 2; ++tp){
      const int t = tt[tp];
      f32x4 t2[3];
      #pragma unroll
      for (int i = 0; i < 3; ++i) t2[i] = (f32x4)0.0f;
      #pragma unroll
      for (int kt = 0; kt < 2; ++kt){
        bf16x8 a = ld8(&Sg[wave][tp][li][kt*32 + 8*lg]);
        #pragma unroll
        for (int nt = 0; nt < 3; ++nt) t2[nt] = MFMA16(a, lwF[nt][kt], t2[nt]);
      }
      #pragma unroll
      for (int nt = 0; nt < 3; ++nt){
        u16x4 w;
        #pragma unroll
        for (int r = 0; r < 4; ++r) w[r] = f2bf(t2[nt][r]);
        *(u16x4*)&t2T[nt*16 + li][t*16 + 4*lg] = w;
      }
    }
    __syncthreads();   // t2T complete

    // ---- phase C: hu = gw x t2T (both tiles); h = norm(clip(h*hu)); hl
    f32x4 hu[2][3];
    #pragma unroll
    for (int tp = 0; tp < 2; ++tp){
      const int t = tt[tp];
      #pragma unroll
      for (int i = 0; i < 3; ++i) hu[tp][i] = (f32x4)0.0f;
      const uint16_t* gA = gwh + (size_t)(t*16 + li)*SP + 8*lg;
      #pragma unroll
      for (int kt = 0; kt < 7; ++kt){
        bf16x8 a = ld8(gA + kt*32);
        #pragma unroll
        for (int nt = 0; nt < 3; ++nt)
          hu[tp][nt] = MFMA16(a, ld8(&t2T[nt*16 + li][kt*32 + 8*lg]), hu[tp][nt]);
      }
    }
    #pragma unroll
    for (int tp = 0; tp < 2; ++tp){
      float s[4] = {0.f,0.f,0.f,0.f};
      #pragma unroll
      for (int nt = 0; nt < 3; ++nt)
        #pragma unroll
        for (int r = 0; r < 4; ++r){
          float v = fmaxf(hr[tp][nt][r] * hu[tp][nt][r], 1e-6f);
          hr[tp][nt][r] = v; s[r] += v;
        }
      #pragma unroll
      for (int r = 0; r < 4; ++r) s[r] = frcp(dpp_add16(s[r]));
      #pragma unroll
      for (int nt = 0; nt < 3; ++nt)
        #pragma unroll
        for (int r = 0; r < 4; ++r){
          hr[tp][nt][r] *= s[r];
          Sg[wave][tp][4*lg + r][nt*16 + li] = f2bf(hr[tp][nt][r]);
        }
    }
    lds_fence();
    #pragma unroll
    for (int tp = 0; tp < 2; ++tp){
      const int t = tt[tp];
      f32x4 hl[3];
      #pragma unroll
      for (int i = 0; i < 3; ++i) hl[i] = (f32x4)0.0f;
      #pragma unroll
      for (int kt = 0; kt < 2; ++kt){
        bf16x8 a = ld8(&Sg[wave][tp][li][kt*32 + 8*lg]);
        #pragma unroll
        for (int nt = 0; nt < 3; ++nt) hl[nt] = MFMA16(a, lwtF[nt][kt], hl[nt]);
      }
      #pragma unroll
      for (int nt = 0; nt < 3; ++nt){
        u16x4 w;
        #pragma unroll
        for (int r = 0; r < 4; ++r) w[r] = f2bf(hl[nt][r]);
        *(u16x4*)&hlT[nt*16 + li][t*16 + 4*lg] = w;
      }
    }
    __syncthreads();   // hlT complete for next iteration
  }

  // write back h from registers (rows < 196; pad rows/cols already zero)
  #pragma unroll
  for (int tp = 0; tp < 2; ++tp){
    const int t = tt[tp];
    #pragma unroll
    for (int nt = 0; nt < 3; ++nt)
      #pragma unroll
      for (int r = 0; r < 4; ++r){
        int row = t*16 + 4*lg + r;
        if (row < NS)
          hrow[(size_t)row*EP + nt*16 + li] = f2bf(hr[tp][nt][r]);
      }
  }
}

// ---------------- output GEMM ----------------
// 8 waves: wave = mt*2+nh; 16 rows x 192 cols per wave; acc = 48 VGPR.
__global__ __launch_bounds__(512) void k_out(const uint16_t* __restrict__ h_b,
    const uint16_t* __restrict__ ow_b, const float* __restrict__ obv,
    float* __restrict__ out){
  const int wave = threadIdx.x >> 6, lane = threadIdx.x & 63;
  const int lg = lane >> 4, li = lane & 15;
  const int mt = wave >> 1, nh = wave & 1;
  const int m0 = blockIdx.x * 64 + mt * 16;
  const int m = m0 + li;
  const int b = m / NS, si = m - b*NS;
  f32x4 acc[12];
  #pragma unroll
  for (int i = 0; i < 12; ++i) acc[i] = (f32x4)0.0f;
  for (int kt = 0; kt < 12; ++kt){
    int ks = kt*32 + 8*lg;
    int hh = ks / NEH, f = ks - hh*NEH;
    bf16x8 a = ld8(h_b + ((size_t)(b*NH + hh)*SP + si)*EP + f);
    #pragma unroll
    for (int nt = 0; nt < 12; ++nt){
      bf16x8 bb = ld8(ow_b + (size_t)((nh*12 + nt)*16 + li)*NF + kt*32 + 8*lg);
      acc[nt] = MFMA16(a, bb, acc[nt]);
    }
  }
  #pragma unroll
  for (int nt = 0; nt < 12; ++nt){
    float bias = obv[(nh*12 + nt)*16 + li];
    #pragma unroll
    for (int r = 0; r < 4; ++r)
      out[(size_t)(m0 + 4*lg + r)*NF + (nh*12 + nt)*16 + li] = acc[nt][r] + bias;
  }
}

// ---------------- launch ----------------
extern "C" void kernel_launch(void* const* d_in, const int* in_sizes, int n_in,
                              void* d_out, int out_size, void* d_ws, size_t ws_size,
                              hipStream_t stream){
  const float* x   = (const float*)d_in[0];
  const float* h0  = (const float*)d_in[1];
  const float* ew  = (const float*)d_in[2];
  const float* eb  = (const float*)d_in[3];
  const float* lw  = (const float*)d_in[4];
  const float* gw  = (const float*)d_in[5];
  const float* ow  = (const float*)d_in[6];
  const float* obv = (const float*)d_in[7];
  float* out = (float*)d_out;

  char* w = (char*)d_ws;
  size_t o_inp = 0;
  size_t o_hb  = o_inp + (size_t)NBH*NT*64*12*2;   // inp_fm: 40.9 MB
  size_t o_gw  = o_hb  + (size_t)NBH*SP*EP*2;      // h_b:    58.7 MB
  size_t o_gwt = o_gw  + (size_t)NH*SP*SP*2;
  size_t o_lw  = o_gwt + (size_t)NH*SP*SP*2;
  size_t o_lwt = o_lw  + (size_t)EP*EP*2;
  size_t o_ew  = o_lwt + (size_t)EP*EP*2;
  size_t o_ow  = o_ew  + (size_t)NF*NF*2;
  size_t total = o_ow  + (size_t)NF*NF*2;
  if (ws_size < total) return;

  uint16_t* inp_fm = (uint16_t*)(w + o_inp);
  uint16_t* h_b    = (uint16_t*)(w + o_hb);
  uint16_t* gw_b   = (uint16_t*)(w + o_gw);
  uint16_t* gwt_b  = (uint16_t*)(w + o_gwt);
  uint16_t* lw_b   = (uint16_t*)(w + o_lw);
  uint16_t* lwt_b  = (uint16_t*)(w + o_lwt);
  uint16_t* ew_b   = (uint16_t*)(w + o_ew);
  uint16_t* ow_b   = (uint16_t*)(w + o_ow);

  k_prep_gw<<<(NH*SP*SP + 255)/256, 256, 0, stream>>>(gw, gw_b, gwt_b);
  k_prep_small<<<(NF*NF + 255)/256, 256, 0, stream>>>(lw, ew, ow, lw_b, lwt_b, ew_b, ow_b);
  k_prep_h<<<(NBH*SP + 255)/256, 256, 0, stream>>>(h0, h_b);
  k_embed<<<NBS/64, 512, 0, stream>>>(x, ew_b, eb, inp_fm);
  k_main<<<NBH, 448, 0, stream>>>(gw_b, gwt_b, lw_b, lwt_b, inp_fm, h_b);
  k_out<<<NBS/64, 512, 0, stream>>>(h_b, ow_b, obv, out);
}

// Round 8
// 735.368 us; speedup vs baseline: 2.3131x; 1.0402x over previous
//
#include <hip/hip_runtime.h>
#include <stdint.h>

#define NB   256      // batch
#define NS   196      // seq len (= hidden seq)
#define NF   384      // in/out features
#define NH   8        // heads
#define NEH  48       // per-head dim
#define NIT  10
#define SP   224      // padded seq (14 tiles of 16)
#define EP   64       // padded per-head dim
#define NBH  2048     // NB*NH
#define NBS  50176    // NB*NS
#define NT   13       // inp tiles (rows<196 only)

using f32x4  = __attribute__((ext_vector_type(4))) float;
using u16x8  = __attribute__((ext_vector_type(8))) uint16_t;
using u16x4  = __attribute__((ext_vector_type(4))) uint16_t;
using bf16x8 = __attribute__((ext_vector_type(8))) __bf16;

static __device__ __forceinline__ float bf2f(uint16_t u){
  union { uint32_t u32; float f; } c; c.u32 = (uint32_t)u << 16; return c.f;
}
static __device__ __forceinline__ uint16_t f2bf(float f){
  __bf16 h = (__bf16)f;
  return __builtin_bit_cast(uint16_t, h);
}
static __device__ __forceinline__ float frcp(float f){
  return __builtin_amdgcn_rcpf(f);
}
static __device__ __forceinline__ bf16x8 ld8(const uint16_t* p){
  return __builtin_bit_cast(bf16x8, *(const u16x8*)p);
}
static __device__ __forceinline__ void lds_fence(){
  asm volatile("s_waitcnt lgkmcnt(0)" ::: "memory");
}
// 16-lane sum via DPP (4 VALU adds, no LDS traffic)
static __device__ __forceinline__ float dpp_add16(float x){
  int v = __builtin_bit_cast(int, x);
  x += __builtin_bit_cast(float, __builtin_amdgcn_update_dpp(0, v, 0xB1, 0xF, 0xF, false));
  v = __builtin_bit_cast(int, x);
  x += __builtin_bit_cast(float, __builtin_amdgcn_update_dpp(0, v, 0x4E, 0xF, 0xF, false));
  v = __builtin_bit_cast(int, x);
  x += __builtin_bit_cast(float, __builtin_amdgcn_update_dpp(0, v, 0x141, 0xF, 0xF, false));
  v = __builtin_bit_cast(int, x);
  x += __builtin_bit_cast(float, __builtin_amdgcn_update_dpp(0, v, 0x140, 0xF, 0xF, false));
  return x;
}
#define MFMA16(a,b,c) __builtin_amdgcn_mfma_f32_16x16x32_bf16((a),(b),(c),0,0,0)

// ---------------- prep kernels ----------------

__global__ void k_prep_gw(const float* __restrict__ gw, uint16_t* __restrict__ gw_b,
                          uint16_t* __restrict__ gwt_b){
  int idx = blockIdx.x * 256 + threadIdx.x;
  if (idx >= NH*SP*SP) return;
  int h = idx / (SP*SP);
  int r = (idx / SP) % SP;   // o
  int c = idx % SP;          // i
  float v = (r < NS && c < NS) ? gw[((size_t)h*NS + r)*NS + c] : 0.f;
  uint16_t bv = f2bf(v);
  gw_b[idx] = bv;
  gwt_b[((size_t)h*SP + c)*SP + r] = bv;
}

__global__ void k_prep_small(const float* __restrict__ lw, const float* __restrict__ ew,
                             const float* __restrict__ ow,
                             uint16_t* __restrict__ lw_b, uint16_t* __restrict__ lwt_b,
                             uint16_t* __restrict__ ew_b, uint16_t* __restrict__ ow_b){
  int idx = blockIdx.x * 256 + threadIdx.x;
  if (idx < EP*EP){
    int f = idx >> 6, e = idx & 63;
    float v = (f < NEH && e < NEH) ? lw[f*NEH + e] : 0.f;
    uint16_t bv = f2bf(v);
    lw_b[f*EP + e] = bv;     // [f][e]
    lwt_b[e*EP + f] = bv;    // [e][f]
  }
  if (idx < NF*NF){
    ew_b[idx] = f2bf(ew[idx]);
    ow_b[idx] = f2bf(ow[idx]);
  }
}

// ---------------- embed GEMM + input prep ----------------
// 8 waves; inp written FRAGMENT-MAJOR: inp_fm[bh][t][lane][slot],
// lane=(wi>>2)*16+li, slot=j*4+(wi&3), wi=si%16
__global__ __launch_bounds__(512) void k_embed(const float* __restrict__ x,
    const uint16_t* __restrict__ ew_b, const float* __restrict__ eb,
    uint16_t* __restrict__ inp_fm){
  const int wave = threadIdx.x >> 6, lane = threadIdx.x & 63;
  const int lg = lane >> 4, li = lane & 15;
  const int mt = wave >> 1, nh = wave & 1;
  const int m0 = blockIdx.x * 64 + mt * 16;
  f32x4 acc[12];
  #pragma unroll
  for (int i = 0; i < 12; ++i) acc[i] = (f32x4)0.0f;
  const float* ap = x + (size_t)(m0 + li) * NF + 8*lg;
  for (int kt = 0; kt < 12; ++kt){
    f32x4 a0 = *(const f32x4*)(ap + kt*32);
    f32x4 a1 = *(const f32x4*)(ap + kt*32 + 4);
    u16x8 au;
    #pragma unroll
    for (int j = 0; j < 4; ++j){ au[j] = f2bf(a0[j]); au[j+4] = f2bf(a1[j]); }
    bf16x8 a = __builtin_bit_cast(bf16x8, au);
    #pragma unroll
    for (int nt = 0; nt < 12; ++nt){
      bf16x8 b = ld8(ew_b + (size_t)((nh*12 + nt)*16 + li)*NF + kt*32 + 8*lg);
      acc[nt] = MFMA16(a, b, acc[nt]);
    }
  }
  #pragma unroll
  for (int hl = 0; hl < 4; ++hl){
    int hh = nh*4 + hl;
    float xec[3][4];
    float s[4] = {0.f, 0.f, 0.f, 0.f};
    #pragma unroll
    for (int j = 0; j < 3; ++j){
      int nt = hl*3 + j;
      float bias = eb[(nh*12 + nt)*16 + li];
      #pragma unroll
      for (int r = 0; r < 4; ++r){
        float v = fmaxf(acc[nt][r] + bias, 1e-6f);
        xec[j][r] = v; s[r] += v;
      }
    }
    #pragma unroll
    for (int r = 0; r < 4; ++r) s[r] = dpp_add16(s[r]);
    #pragma unroll
    for (int r = 0; r < 4; ++r){
      int m = m0 + 4*lg + r;
      int b = m / NS, si = m - b*NS;
      int t = si >> 4, wi = si & 15;
      int lanep = (wi >> 2)*16 + li;
      float inv = frcp(s[r]);
      size_t base = ((size_t)((b*NH + hh)*NT + t)*64 + lanep)*12 + (wi & 3);
      #pragma unroll
      for (int j = 0; j < 3; ++j)
        inp_fm[base + j*4] = f2bf(xec[j][r] * inv);
    }
  }
}

// ---------------- main NNMF fixed-point kernel ----------------
// One block per (b,h). 7 waves x 2 tiles = 14 tiles (incl. zero pad tile 13).
// rec = gwT x (h x lw) via maintained hl; h fp32 in regs; inp in regs.
// KEY (r8): rec/hu B-fragments (hlT/t2T) are IDENTICAL for both tiles ->
// load once per kt, use for both A rows (42 -> 21 ds_read_b128 per phase;
// LDS pipe was ~75% busy and is the bottleneck). h0 loaded directly
// (k_prep_h fused; pad-col safety comes from gw_b zero padding).
__global__ __launch_bounds__(448) void k_main(
    const float*    __restrict__ h0,     // [B][NS][H][NEH]
    const uint16_t* __restrict__ gw_b,   // [H][SP][SP] (o,i)
    const uint16_t* __restrict__ gwt_b,  // [H][SP][SP] (i,o)
    const uint16_t* __restrict__ lw_b,   // [EP][EP] (f,e)
    const uint16_t* __restrict__ lwt_b,  // [EP][EP] (e,f)
    const uint16_t* __restrict__ inp_fm, // [BH][13][64][12]
    uint16_t* __restrict__ h_b)          // [BH][SP][EP] (output for k_out)
{
  __shared__ __align__(16) uint16_t hlT[48][232];      // (h x lw)^T  [e][o]
  __shared__ __align__(16) uint16_t t2T[48][232];      // t2^T        [f][i]
  __shared__ __align__(16) uint16_t Sg[7][2][16][72];  // per-wave staging

  const int bh = blockIdx.x;
  const int b  = bh >> 3;
  const int hh = bh & 7;
  const int tid = threadIdx.x;
  const int wave = tid >> 6;
  const int lane = tid & 63;
  const int lg = lane >> 4;
  const int li = lane & 15;
  const int tt[2] = {wave, wave + 7};

  // zero staging K-pad cols 48..63 (never rewritten; kt=1 A-frag reads them)
  {
    u16x4 z = {0,0,0,0};
    *(u16x4*)&Sg[wave][0][li][48 + 4*lg] = z;
    *(u16x4*)&Sg[wave][1][li][48 + 4*lg] = z;
  }

  // local-weight B-fragments (constant across iterations)
  bf16x8 lwtF[3][2], lwF[3][2];
  #pragma unroll
  for (int nt = 0; nt < 3; ++nt)
    #pragma unroll
    for (int kt = 0; kt < 2; ++kt){
      lwtF[nt][kt] = ld8(lwt_b + (size_t)(nt*16 + li)*EP + kt*32 + 8*lg); // B[k=f][n=e]
      lwF [nt][kt] = ld8(lw_b  + (size_t)(nt*16 + li)*EP + kt*32 + 8*lg); // B[k=e][n=f]
    }

  // persistent inp fragments (iteration-invariant): pad tile 13 -> zeros
  u16x4 ip[2][3];
  #pragma unroll
  for (int tp = 0; tp < 2; ++tp){
    const int t = tt[tp];
    if (t < NT){
      const uint16_t* ipp = inp_fm + ((size_t)(bh*NT + t)*64 + lg*16 + li)*12;
      ip[tp][0] = *(const u16x4*)(ipp);
      ip[tp][1] = *(const u16x4*)(ipp + 4);
      ip[tp][2] = *(const u16x4*)(ipp + 8);
    } else {
      u16x4 z = {0,0,0,0};
      ip[tp][0] = z; ip[tp][1] = z; ip[tp][2] = z;
    }
  }

  // h init straight from h0 (fp32): fragment layout row=t*16+4lg+r,
  // col=nt*16+li; L1-normalize per row via dpp_add16; stage bf16 to Sg
  float hr[2][3][4];
  #pragma unroll
  for (int tp = 0; tp < 2; ++tp){
    const int t = tt[tp];
    float s[4] = {0.f,0.f,0.f,0.f};
    #pragma unroll
    for (int nt = 0; nt < 3; ++nt)
      #pragma unroll
      for (int r = 0; r < 4; ++r){
        int row = t*16 + 4*lg + r;
        float v = 0.f;
        if (row < NS)
          v = h0[(((size_t)(b*NS + row))*NH + hh)*NEH + nt*16 + li];
        hr[tp][nt][r] = v;
        s[r] += fabsf(v);
      }
    #pragma unroll
    for (int r = 0; r < 4; ++r) s[r] = frcp(fmaxf(dpp_add16(s[r]), 1e-12f));
    #pragma unroll
    for (int nt = 0; nt < 3; ++nt)
      #pragma unroll
      for (int r = 0; r < 4; ++r){
        hr[tp][nt][r] *= s[r];
        Sg[wave][tp][4*lg + r][nt*16 + li] = f2bf(hr[tp][nt][r]);
      }
  }
  lds_fence();
  // initial hl = h x lw -> hlT
  #pragma unroll
  for (int tp = 0; tp < 2; ++tp){
    const int t = tt[tp];
    f32x4 hl[3];
    #pragma unroll
    for (int i = 0; i < 3; ++i) hl[i] = (f32x4)0.0f;
    #pragma unroll
    for (int kt = 0; kt < 2; ++kt){
      bf16x8 a = ld8(&Sg[wave][tp][li][kt*32 + 8*lg]);
      #pragma unroll
      for (int nt = 0; nt < 3; ++nt) hl[nt] = MFMA16(a, lwtF[nt][kt], hl[nt]);
    }
    #pragma unroll
    for (int nt = 0; nt < 3; ++nt){
      u16x4 w;
      #pragma unroll
      for (int r = 0; r < 4; ++r) w[r] = f2bf(hl[nt][r]);
      *(u16x4*)&hlT[nt*16 + li][t*16 + 4*lg] = w;
    }
  }

  const uint16_t* __restrict__ gwh  = gw_b  + (size_t)hh * SP * SP;
  const uint16_t* __restrict__ gwth = gwt_b + (size_t)hh * SP * SP;
  const uint16_t* gA0t = gwth + (size_t)(tt[0]*16 + li)*SP + 8*lg;
  const uint16_t* gA1t = gwth + (size_t)(tt[1]*16 + li)*SP + 8*lg;
  const uint16_t* gA0  = gwh  + (size_t)(tt[0]*16 + li)*SP + 8*lg;
  const uint16_t* gA1  = gwh  + (size_t)(tt[1]*16 + li)*SP + 8*lg;
  __syncthreads();   // hlT ready

  for (int it = 0; it < NIT; ++it){
    // ---- phase B: rec = gwt x hlT (B-frags shared across tiles)
    f32x4 rec[2][3];
    #pragma unroll
    for (int tp = 0; tp < 2; ++tp)
      #pragma unroll
      for (int i = 0; i < 3; ++i) rec[tp][i] = (f32x4)0.0f;
    #pragma unroll
    for (int kt = 0; kt < 7; ++kt){
      bf16x8 b0 = ld8(&hlT[ 0 + li][kt*32 + 8*lg]);
      bf16x8 b1 = ld8(&hlT[16 + li][kt*32 + 8*lg]);
      bf16x8 b2 = ld8(&hlT[32 + li][kt*32 + 8*lg]);
      bf16x8 a0 = ld8(gA0t + kt*32);
      bf16x8 a1 = ld8(gA1t + kt*32);
      rec[0][0] = MFMA16(a0, b0, rec[0][0]);
      rec[0][1] = MFMA16(a0, b1, rec[0][1]);
      rec[0][2] = MFMA16(a0, b2, rec[0][2]);
      rec[1][0] = MFMA16(a1, b0, rec[1][0]);
      rec[1][1] = MFMA16(a1, b1, rec[1][1]);
      rec[1][2] = MFMA16(a1, b2, rec[1][2]);
    }
    #pragma unroll
    for (int tp = 0; tp < 2; ++tp){
      float s[4] = {0.f,0.f,0.f,0.f};
      float rv[3][4];
      #pragma unroll
      for (int nt = 0; nt < 3; ++nt)
        #pragma unroll
        for (int r = 0; r < 4; ++r){
          float v = fmaxf(rec[tp][nt][r], 1e-6f);
          rv[nt][r] = v; s[r] += v;
        }
      #pragma unroll
      for (int r = 0; r < 4; ++r) s[r] = dpp_add16(s[r]);
      #pragma unroll
      for (int r = 0; r < 4; ++r){
        Sg[wave][tp][4*lg + r][ 0 + li] = f2bf(bf2f(ip[tp][0][r]) * s[r] * frcp(rv[0][r]));
        Sg[wave][tp][4*lg + r][16 + li] = f2bf(bf2f(ip[tp][1][r]) * s[r] * frcp(rv[1][r]));
        Sg[wave][tp][4*lg + r][32 + li] = f2bf(bf2f(ip[tp][2][r]) * s[r] * frcp(rv[2][r]));
      }
    }
    lds_fence();
    #pragma unroll
    for (int tp = 0; tp < 2; ++tp){
      const int t = tt[tp];
      f32x4 t2[3];
      #pragma unroll
      for (int i = 0; i < 3; ++i) t2[i] = (f32x4)0.0f;
      #pragma unroll
      for (int kt = 0; kt < 2; ++kt){
        bf16x8 a = ld8(&Sg[wave][tp][li][kt*32 + 8*lg]);
        #pragma unroll
        for (int nt = 0; nt < 3; ++nt) t2[nt] = MFMA16(a, lwF[nt][kt], t2[nt]);
      }
      #pragma unroll
      for (int nt = 0; nt < 3; ++nt){
        u16x4 w;
        #pragma unroll
        for (int r = 0; r < 4; ++r) w[r] = f2bf(t2[nt][r]);
        *(u16x4*)&t2T[nt*16 + li][t*16 + 4*lg] = w;
      }
    }
    __syncthreads();   // t2T complete

    // ---- phase C: hu = gw x t2T (B-frags shared across tiles)
    f32x4 hu[2][3];
    #pragma unroll
    for (int tp = 0; tp < 2; ++tp)
      #pragma unroll
      for (int i = 0; i < 3; ++i) hu[tp][i] = (f32x4)0.0f;
    #pragma unroll
    for (int kt = 0; kt < 7; ++kt){
      bf16x8 b0 = ld8(&t2T[ 0 + li][kt*32 + 8*lg]);
      bf16x8 b1 = ld8(&t2T[16 + li][kt*32 + 8*lg]);
      bf16x8 b2 = ld8(&t2T[32 + li][kt*32 + 8*lg]);
      bf16x8 a0 = ld8(gA0 + kt*32);
      bf16x8 a1 = ld8(gA1 + kt*32);
      hu[0][0] = MFMA16(a0, b0, hu[0][0]);
      hu[0][1] = MFMA16(a0, b1, hu[0][1]);
      hu[0][2] = MFMA16(a0, b2, hu[0][2]);
      hu[1][0] = MFMA16(a1, b0, hu[1][0]);
      hu[1][1] = MFMA16(a1, b1, hu[1][1]);
      hu[1][2] = MFMA16(a1, b2, hu[1][2]);
    }
    #pragma unroll
    for (int tp = 0; tp < 2; ++tp){
      float s[4] = {0.f,0.f,0.f,0.f};
      #pragma unroll
      for (int nt = 0; nt < 3; ++nt)
        #pragma unroll
        for (int r = 0; r < 4; ++r){
          float v = fmaxf(hr[tp][nt][r] * hu[tp][nt][r], 1e-6f);
          hr[tp][nt][r] = v; s[r] += v;
        }
      #pragma unroll
      for (int r = 0; r < 4; ++r) s[r] = frcp(dpp_add16(s[r]));
      #pragma unroll
      for (int nt = 0; nt < 3; ++nt)
        #pragma unroll
        for (int r = 0; r < 4; ++r){
          hr[tp][nt][r] *= s[r];
          Sg[wave][tp][4*lg + r][nt*16 + li] = f2bf(hr[tp][nt][r]);
        }
    }
    lds_fence();
    #pragma unroll
    for (int tp = 0; tp < 2; ++tp){
      const int t = tt[tp];
      f32x4 hl[3];
      #pragma unroll
      for (int i = 0; i < 3; ++i) hl[i] = (f32x4)0.0f;
      #pragma unroll
      for (int kt = 0; kt < 2; ++kt){
        bf16x8 a = ld8(&Sg[wave][tp][li][kt*32 + 8*lg]);
        #pragma unroll
        for (int nt = 0; nt < 3; ++nt) hl[nt] = MFMA16(a, lwtF[nt][kt], hl[nt]);
      }
      #pragma unroll
      for (int nt = 0; nt < 3; ++nt){
        u16x4 w;
        #pragma unroll
        for (int r = 0; r < 4; ++r) w[r] = f2bf(hl[nt][r]);
        *(u16x4*)&hlT[nt*16 + li][t*16 + 4*lg] = w;
      }
    }
    __syncthreads();   // hlT complete for next iteration
  }

  // write back h (rows < 196 only; k_out reads only those rows/cols)
  uint16_t* __restrict__ hrow = h_b + (size_t)bh * SP * EP;
  #pragma unroll
  for (int tp = 0; tp < 2; ++tp){
    const int t = tt[tp];
    #pragma unroll
    for (int nt = 0; nt < 3; ++nt)
      #pragma unroll
      for (int r = 0; r < 4; ++r){
        int row = t*16 + 4*lg + r;
        if (row < NS)
          hrow[(size_t)row*EP + nt*16 + li] = f2bf(hr[tp][nt][r]);
      }
  }
}

// ---------------- output GEMM ----------------
__global__ __launch_bounds__(512) void k_out(const uint16_t* __restrict__ h_b,
    const uint16_t* __restrict__ ow_b, const float* __restrict__ obv,
    float* __restrict__ out){
  const int wave = threadIdx.x >> 6, lane = threadIdx.x & 63;
  const int lg = lane >> 4, li = lane & 15;
  const int mt = wave >> 1, nh = wave & 1;
  const int m0 = blockIdx.x * 64 + mt * 16;
  const int m = m0 + li;
  const int b = m / NS, si = m - b*NS;
  f32x4 acc[12];
  #pragma unroll
  for (int i = 0; i < 12; ++i) acc[i] = (f32x4)0.0f;
  for (int kt = 0; kt < 12; ++kt){
    int ks = kt*32 + 8*lg;
    int hh = ks / NEH, f = ks - hh*NEH;
    bf16x8 a = ld8(h_b + ((size_t)(b*NH + hh)*SP + si)*EP + f);
    #pragma unroll
    for (int nt = 0; nt < 12; ++nt){
      bf16x8 bb = ld8(ow_b + (size_t)((nh*12 + nt)*16 + li)*NF + kt*32 + 8*lg);
      acc[nt] = MFMA16(a, bb, acc[nt]);
    }
  }
  #pragma unroll
  for (int nt = 0; nt < 12; ++nt){
    float bias = obv[(nh*12 + nt)*16 + li];
    #pragma unroll
    for (int r = 0; r < 4; ++r)
      out[(size_t)(m0 + 4*lg + r)*NF + (nh*12 + nt)*16 + li] = acc[nt][r] + bias;
  }
}

// ---------------- launch ----------------
extern "C" void kernel_launch(void* const* d_in, const int* in_sizes, int n_in,
                              void* d_out, int out_size, void* d_ws, size_t ws_size,
                              hipStream_t stream){
  const float* x   = (const float*)d_in[0];
  const float* h0  = (const float*)d_in[1];
  const float* ew  = (const float*)d_in[2];
  const float* eb  = (const float*)d_in[3];
  const float* lw  = (const float*)d_in[4];
  const float* gw  = (const float*)d_in[5];
  const float* ow  = (const float*)d_in[6];
  const float* obv = (const float*)d_in[7];
  float* out = (float*)d_out;

  char* w = (char*)d_ws;
  size_t o_inp = 0;
  size_t o_hb  = o_inp + (size_t)NBH*NT*64*12*2;   // inp_fm: 40.9 MB
  size_t o_gw  = o_hb  + (size_t)NBH*SP*EP*2;      // h_b:    58.7 MB
  size_t o_gwt = o_gw  + (size_t)NH*SP*SP*2;
  size_t o_lw  = o_gwt + (size_t)NH*SP*SP*2;
  size_t o_lwt = o_lw  + (size_t)EP*EP*2;
  size_t o_ew  = o_lwt + (size_t)EP*EP*2;
  size_t o_ow  = o_ew  + (size_t)NF*NF*2;
  size_t total = o_ow  + (size_t)NF*NF*2;
  if (ws_size < total) return;

  uint16_t* inp_fm = (uint16_t*)(w + o_inp);
  uint16_t* h_b    = (uint16_t*)(w + o_hb);
  uint16_t* gw_b   = (uint16_t*)(w + o_gw);
  uint16_t* gwt_b  = (uint16_t*)(w + o_gwt);
  uint16_t* lw_b   = (uint16_t*)(w + o_lw);
  uint16_t* lwt_b  = (uint16_t*)(w + o_lwt);
  uint16_t* ew_b   = (uint16_t*)(w + o_ew);
  uint16_t* ow_b   = (uint16_t*)(w + o_ow);

  k_prep_gw<<<(NH*SP*SP + 255)/256, 256, 0, stream>>>(gw, gw_b, gwt_b);
  k_prep_small<<<(NF*NF + 255)/256, 256, 0, stream>>>(lw, ew, ow, lw_b, lwt_b, ew_b, ow_b);
  k_embed<<<NBS/64, 512, 0, stream>>>(x, ew_b, eb, inp_fm);
  k_main<<<NBH, 448, 0, stream>>>(h0, gw_b, gwt_b, lw_b, lwt_b, inp_fm, h_b);
  k_out<<<NBS/64, 512, 0, stream>>>(h_b, ow_b, obv, out);
}